// Round 6
// baseline (658.980 us; speedup 1.0000x reference)
//
#include <hip/hip_runtime.h>
#include <math.h>

#define SBS 256
#define SIT 8
#define SCHUNK (SBS*SIT)

typedef __bf16 bf16x8 __attribute__((ext_vector_type(8)));
typedef float  f32x4  __attribute__((ext_vector_type(4)));

__device__ __forceinline__ unsigned short f2bf(float f){
  unsigned u = __float_as_uint(f);
  unsigned r = (u + 0x7fffu + ((u>>16)&1u)) >> 16;
  return (unsigned short)r;
}
__device__ __forceinline__ float bflo(unsigned v){ return __uint_as_float(v<<16); }
__device__ __forceinline__ float bfhi(unsigned v){ return __uint_as_float(v & 0xffff0000u); }

// ---------------- gcn_norm preprocessing ----------------

__global__ void k_count(const int* __restrict__ col, int* __restrict__ deg, int E){
  int e = blockIdx.x*256 + threadIdx.x;
  if(e < E) atomicAdd(&deg[col[e]], 1);
}

__global__ void k_dis(const int* __restrict__ deg, float* __restrict__ dis, int N){
  int i = blockIdx.x*256 + threadIdx.x;
  if(i < N){ int d = deg[i]; dis[i] = d > 0 ? rsqrtf((float)d) : 0.f; }
}

__global__ void k_scan_a(const int* __restrict__ deg, int* __restrict__ bsums, int N){
  __shared__ int ls[SBS/64];
  int base = blockIdx.x*SCHUNK + threadIdx.x*SIT;
  int s = 0;
  #pragma unroll
  for(int j=0;j<SIT;j++){ int i=base+j; if(i<N) s += deg[i]; }
  #pragma unroll
  for(int o=32;o>0;o>>=1) s += __shfl_down(s,o);
  int lane = threadIdx.x & 63, w = threadIdx.x >> 6;
  if(lane==0) ls[w]=s;
  __syncthreads();
  if(threadIdx.x==0){ int t=0; for(int k2=0;k2<SBS/64;k2++) t+=ls[k2]; bsums[blockIdx.x]=t; }
}

__global__ void k_scan_b(const int* __restrict__ bsums, int* __restrict__ boffs,
                         int* __restrict__ rowptr, int NB, int N){
  int lane = threadIdx.x;
  int v = (lane < NB) ? bsums[lane] : 0;
  int incl = v;
  #pragma unroll
  for(int o=1;o<64;o<<=1){ int t = __shfl_up(incl,o); if(lane>=o) incl += t; }
  if(lane < NB) boffs[lane] = incl - v;
  if(lane == 63) rowptr[N] = incl;
}

__global__ void k_scan_c(const int* __restrict__ deg, const int* __restrict__ boffs,
                         int* __restrict__ rowptr, int* __restrict__ cur, int N){
  __shared__ int ts[SBS];
  int tid = threadIdx.x;
  int base = blockIdx.x*SCHUNK + tid*SIT;
  int v[SIT]; int s=0;
  #pragma unroll
  for(int j=0;j<SIT;j++){ int i=base+j; int d=(i<N)?deg[i]:0; v[j]=s; s+=d; }
  ts[tid]=s; __syncthreads();
  for(int o=1;o<SBS;o<<=1){
    int t=(tid>=o)?ts[tid-o]:0; __syncthreads();
    ts[tid]+=t; __syncthreads();
  }
  int texcl = ts[tid]-s;
  int off = boffs[blockIdx.x]+texcl;
  #pragma unroll
  for(int j=0;j<SIT;j++){ int i=base+j; if(i<N){int r=off+v[j]; rowptr[i]=r; cur[i]=r;} }
}

// edge record = src index only (4B scattered store)
__global__ void k_fill(const int* __restrict__ row, const int* __restrict__ col,
                       int* __restrict__ cur, unsigned* __restrict__ ed, int E){
  int e = blockIdx.x*256+threadIdx.x;
  if(e<E){
    int r=row[e], c=col[e];
    int p = atomicAdd(&cur[c],1);
    ed[p] = (unsigned)r;
  }
}

// ---------------- casts ----------------

__global__ void k_cast_x(const float* __restrict__ x, ushort* __restrict__ xb, int n4){
  int t = blockIdx.x*256 + threadIdx.x;
  if(t < n4){
    float4 v = ((const float4*)x)[t];
    uint2 o;
    o.x = (unsigned)f2bf(v.x) | ((unsigned)f2bf(v.y)<<16);
    o.y = (unsigned)f2bf(v.z) | ((unsigned)f2bf(v.w)<<16);
    ((uint2*)xb)[t] = o;
  }
}

// w1 [4][128][128] (s,kin,n) -> w1t [128][512] (n, s*128+kin)
__global__ void k_castw1(const float* __restrict__ w1, ushort* __restrict__ w1t){
  int i = blockIdx.x*256 + threadIdx.x;   // 65536
  int n = i & 127, kin = (i>>7)&127, s = i>>14;
  w1t[n*512 + s*128 + kin] = f2bf(w1[i]);
}

// w2 [4][128][40] -> w2t [256][128]
__global__ void k_castw2(const float* __restrict__ w2, ushort* __restrict__ w2t){
  int i = blockIdx.x*256 + threadIdx.x;   // 32768
  int k = i & 127, np = i>>7;
  int s = np>>6, nn = np&63;
  float v = (nn<40) ? w2[(s*128 + k)*40 + nn] : 0.f;
  w2t[i] = f2bf(v);
}

// ------- SpMM width-128: dst[n] = bf16( dis[n] * sum_e dis[r]*src[r] ); 4 edges in flight -------

__global__ void __launch_bounds__(256) k_spmm1(
    const ushort* __restrict__ src, ushort* __restrict__ dst,
    const int* __restrict__ rowptr, const unsigned* __restrict__ ed,
    const float* __restrict__ dis, int N){
  int wid = threadIdx.x>>6, lane = threadIdx.x&63;
  int n = blockIdx.x*4 + wid;
  if(n>=N) return;
  int p = lane>>4, c = lane&15;      // group p handles edges j%4==p; cols 8c..8c+7
  int s = rowptr[n], e = rowptr[n+1];
  float a[8];
  #pragma unroll
  for(int i=0;i<8;i++) a[i]=0.f;
  for(int b=s; b<e; b+=64){
    int m = e-b; if(m>64) m=64;
    int idx = 0; float dr = 0.f;
    if(lane<m){ idx = (int)ed[b+lane]; dr = dis[idx]; }
    int tmax = (m+3)>>2;
    for(int t=0;t<tmax;t++){
      int j = 4*t + p;
      int r = __shfl(idx, j);
      float wg = __shfl(dr, j);      // 0 for j>=m
      uint4 v = *(const uint4*)(src + (size_t)r*128 + c*8);
      a[0]+=wg*bflo(v.x); a[1]+=wg*bfhi(v.x);
      a[2]+=wg*bflo(v.y); a[3]+=wg*bfhi(v.y);
      a[4]+=wg*bflo(v.z); a[5]+=wg*bfhi(v.z);
      a[6]+=wg*bflo(v.w); a[7]+=wg*bfhi(v.w);
    }
  }
  #pragma unroll
  for(int i=0;i<8;i++){ a[i]+=__shfl_xor(a[i],32); a[i]+=__shfl_xor(a[i],16); }
  if(p==0){
    float dc = dis[n];
    uint4 o;
    o.x = (unsigned)f2bf(a[0]*dc) | ((unsigned)f2bf(a[1]*dc)<<16);
    o.y = (unsigned)f2bf(a[2]*dc) | ((unsigned)f2bf(a[3]*dc)<<16);
    o.z = (unsigned)f2bf(a[4]*dc) | ((unsigned)f2bf(a[5]*dc)<<16);
    o.w = (unsigned)f2bf(a[6]*dc) | ((unsigned)f2bf(a[7]*dc)<<16);
    *(uint4*)(dst + (size_t)n*128 + c*8) = o;
  }
}

// ------- SpMM width-64 + add z: t'[n] = dis[n]*sum dis[r]*t[r] + z[n]; 8 edges in flight -------

__global__ void __launch_bounds__(256) k_spmm2(
    const ushort* __restrict__ tprev, int ss,
    const ushort* __restrict__ z, int zs,
    ushort* __restrict__ tnew,
    const int* __restrict__ rowptr, const unsigned* __restrict__ ed,
    const float* __restrict__ dis, int N){
  int wid = threadIdx.x>>6, lane = threadIdx.x&63;
  int n = blockIdx.x*4 + wid;
  if(n>=N) return;
  int p = lane>>3, c = lane&7;       // group p handles edges j%8==p; cols 8c..8c+7
  int s = rowptr[n], e = rowptr[n+1];
  float a[8];
  #pragma unroll
  for(int i=0;i<8;i++) a[i]=0.f;
  for(int b=s; b<e; b+=64){
    int m = e-b; if(m>64) m=64;
    int idx = 0; float dr = 0.f;
    if(lane<m){ idx = (int)ed[b+lane]; dr = dis[idx]; }
    int tmax = (m+7)>>3;
    for(int t=0;t<tmax;t++){
      int j = 8*t + p;
      int r = __shfl(idx, j);
      float wg = __shfl(dr, j);
      uint4 v = *(const uint4*)(tprev + (size_t)r*ss + c*8);
      a[0]+=wg*bflo(v.x); a[1]+=wg*bfhi(v.x);
      a[2]+=wg*bflo(v.y); a[3]+=wg*bfhi(v.y);
      a[4]+=wg*bflo(v.z); a[5]+=wg*bfhi(v.z);
      a[6]+=wg*bflo(v.w); a[7]+=wg*bfhi(v.w);
    }
  }
  #pragma unroll
  for(int i=0;i<8;i++){ a[i]+=__shfl_xor(a[i],32); a[i]+=__shfl_xor(a[i],16); a[i]+=__shfl_xor(a[i],8); }
  if(lane<8){
    float dc = dis[n];
    uint4 vz = *(const uint4*)(z + (size_t)n*zs + c*8);
    a[0]=a[0]*dc+bflo(vz.x); a[1]=a[1]*dc+bfhi(vz.x);
    a[2]=a[2]*dc+bflo(vz.y); a[3]=a[3]*dc+bfhi(vz.y);
    a[4]=a[4]*dc+bflo(vz.z); a[5]=a[5]*dc+bfhi(vz.z);
    a[6]=a[6]*dc+bflo(vz.w); a[7]=a[7]*dc+bfhi(vz.w);
    uint4 o;
    o.x = (unsigned)f2bf(a[0]) | ((unsigned)f2bf(a[1])<<16);
    o.y = (unsigned)f2bf(a[2]) | ((unsigned)f2bf(a[3])<<16);
    o.z = (unsigned)f2bf(a[4]) | ((unsigned)f2bf(a[5])<<16);
    o.w = (unsigned)f2bf(a[6]) | ((unsigned)f2bf(a[7])<<16);
    *(uint4*)(tnew + (size_t)n*64 + c*8) = o;
  }
}

// Final: out = log_softmax(dis[n]*sum dis[r]*t[r] + z0) over cols 0..39, f32 out [N][40]

__global__ void __launch_bounds__(256) k_spmm2_lsm(
    const ushort* __restrict__ tprev, int ss,
    const ushort* __restrict__ z, int zs,
    float* __restrict__ out,
    const int* __restrict__ rowptr, const unsigned* __restrict__ ed,
    const float* __restrict__ dis, int N){
  int wid = threadIdx.x>>6, lane = threadIdx.x&63;
  int n = blockIdx.x*4 + wid;
  if(n>=N) return;
  int p = lane>>3, c = lane&7;
  int s = rowptr[n], e = rowptr[n+1];
  float a[8];
  #pragma unroll
  for(int i=0;i<8;i++) a[i]=0.f;
  for(int b=s; b<e; b+=64){
    int m = e-b; if(m>64) m=64;
    int idx = 0; float dr = 0.f;
    if(lane<m){ idx = (int)ed[b+lane]; dr = dis[idx]; }
    int tmax = (m+7)>>3;
    for(int t=0;t<tmax;t++){
      int j = 8*t + p;
      int r = __shfl(idx, j);
      float wg = __shfl(dr, j);
      uint4 v = *(const uint4*)(tprev + (size_t)r*ss + c*8);
      a[0]+=wg*bflo(v.x); a[1]+=wg*bfhi(v.x);
      a[2]+=wg*bflo(v.y); a[3]+=wg*bfhi(v.y);
      a[4]+=wg*bflo(v.z); a[5]+=wg*bfhi(v.z);
      a[6]+=wg*bflo(v.w); a[7]+=wg*bfhi(v.w);
    }
  }
  #pragma unroll
  for(int i=0;i<8;i++){ a[i]+=__shfl_xor(a[i],32); a[i]+=__shfl_xor(a[i],16); a[i]+=__shfl_xor(a[i],8); }
  float dc = dis[n];
  uint4 vz = *(const uint4*)(z + (size_t)n*zs + c*8);
  a[0]=a[0]*dc+bflo(vz.x); a[1]=a[1]*dc+bfhi(vz.x);
  a[2]=a[2]*dc+bflo(vz.y); a[3]=a[3]*dc+bfhi(vz.y);
  a[4]=a[4]*dc+bflo(vz.z); a[5]=a[5]*dc+bfhi(vz.z);
  a[6]=a[6]*dc+bflo(vz.w); a[7]=a[7]*dc+bfhi(vz.w);
  bool valid = (c < 5);
  float mx = -1e30f;
  #pragma unroll
  for(int i=0;i<8;i++) if(valid) mx = fmaxf(mx, a[i]);
  #pragma unroll
  for(int o=1;o<8;o<<=1) mx = fmaxf(mx, __shfl_xor(mx, o));
  float sum = 0.f;
  #pragma unroll
  for(int i=0;i<8;i++) if(valid) sum += expf(a[i]-mx);
  #pragma unroll
  for(int o=1;o<8;o<<=1) sum += __shfl_xor(sum, o);
  float l = mx + logf(sum);
  if(lane<8 && valid){
    float4 o0, o1;
    o0.x=a[0]-l; o0.y=a[1]-l; o0.z=a[2]-l; o0.w=a[3]-l;
    o1.x=a[4]-l; o1.y=a[5]-l; o1.z=a[6]-l; o1.w=a[7]-l;
    float* op = out + (size_t)n*40 + c*8;
    *(float4*)op = o0;
    *(float4*)(op+4) = o1;
  }
}

// ---------------- MFMA GEMM layer 1 ----------------

#define LDA 72

__global__ void __launch_bounds__(256) k_gemm1(
    const ushort* __restrict__ xb, const ushort* __restrict__ h1,
    const ushort* __restrict__ h2, const ushort* __restrict__ h3,
    const ushort* __restrict__ w1t, const float* __restrict__ bias,
    ushort* __restrict__ outb, int N){
  __shared__ ushort Al[128*LDA];
  __shared__ ushort Bl[128*LDA];
  int tid = threadIdx.x;
  int wid = tid>>6, lane = tid&63;
  int wr = wid>>1, wc = wid&1;
  int lm = lane&15, kg = lane>>4;
  int nbase = blockIdx.x*128;
  f32x4 acc[4][4];
  #pragma unroll
  for(int i=0;i<4;i++)
    #pragma unroll
    for(int j=0;j<4;j++) acc[i][j] = (f32x4){0.f,0.f,0.f,0.f};

  for(int kc=0; kc<8; kc++){
    const ushort* asrc = (kc<2) ? xb : (kc<4) ? h1 : (kc<6) ? h2 : h3;
    int koff = (kc&1)*64;
    __syncthreads();
    #pragma unroll
    for(int i=0;i<4;i++){
      int slot = tid + i*256;
      int r = slot>>3, seg = (slot&7)*8;
      int n = nbase + r;
      uint4 v = make_uint4(0,0,0,0);
      if(n < N) v = *(const uint4*)(asrc + (size_t)n*128 + koff + seg);
      *(uint4*)(&Al[r*LDA + seg]) = v;
    }
    #pragma unroll
    for(int i=0;i<4;i++){
      int slot = tid + i*256;
      int r = slot>>3, seg = (slot&7)*8;
      uint4 v = *(const uint4*)(w1t + (size_t)r*512 + kc*64 + seg);
      *(uint4*)(&Bl[r*LDA + seg]) = v;
    }
    __syncthreads();
    #pragma unroll
    for(int ks=0; ks<2; ks++){
      bf16x8 a[4], b[4];
      #pragma unroll
      for(int f=0; f<4; f++){
        a[f] = *(const bf16x8*)&Al[(wr*64 + f*16 + lm)*LDA + ks*32 + kg*8];
        b[f] = *(const bf16x8*)&Bl[(wc*64 + f*16 + lm)*LDA + ks*32 + kg*8];
      }
      #pragma unroll
      for(int fm=0; fm<4; fm++)
        #pragma unroll
        for(int fn=0; fn<4; fn++)
          acc[fm][fn] = __builtin_amdgcn_mfma_f32_16x16x32_bf16(a[fm], b[fn], acc[fm][fn], 0,0,0);
    }
  }
  int crow0 = (lane>>4)*4;
  #pragma unroll
  for(int fm=0; fm<4; fm++){
    #pragma unroll
    for(int fn=0; fn<4; fn++){
      int col = wc*64 + fn*16 + lm;
      float bv = bias[col];
      #pragma unroll
      for(int j=0;j<4;j++){
        int row = nbase + wr*64 + fm*16 + crow0 + j;
        if(row < N){
          float v = fmaxf(acc[fm][fn][j] + bv, 0.f);
          outb[(size_t)row*128 + col] = f2bf(v);
        }
      }
    }
  }
}

// ------- MFMA GEMM layer 2: zstack[N][256] = out1b @ W2t^T (+b2 on cols<40) -------

__global__ void __launch_bounds__(256) k_gemm2(
    const ushort* __restrict__ ab, const ushort* __restrict__ w2t,
    const float* __restrict__ bias, ushort* __restrict__ z, int N){
  __shared__ ushort Al[128*LDA];
  __shared__ ushort Bl[128*LDA];
  int tid = threadIdx.x;
  int wid = tid>>6, lane = tid&63;
  int wr = wid>>1, wc = wid&1;
  int lm = lane&15, kg = lane>>4;
  int nbase = blockIdx.x*128;
  int cb = blockIdx.y;
  f32x4 acc[4][4];
  #pragma unroll
  for(int i=0;i<4;i++)
    #pragma unroll
    for(int j=0;j<4;j++) acc[i][j] = (f32x4){0.f,0.f,0.f,0.f};

  for(int kc=0; kc<2; kc++){
    int koff = kc*64;
    __syncthreads();
    #pragma unroll
    for(int i=0;i<4;i++){
      int slot = tid + i*256;
      int r = slot>>3, seg = (slot&7)*8;
      int n = nbase + r;
      uint4 v = make_uint4(0,0,0,0);
      if(n < N) v = *(const uint4*)(ab + (size_t)n*128 + koff + seg);
      *(uint4*)(&Al[r*LDA + seg]) = v;
    }
    #pragma unroll
    for(int i=0;i<4;i++){
      int slot = tid + i*256;
      int r = slot>>3, seg = (slot&7)*8;
      uint4 v = *(const uint4*)(w2t + (size_t)(cb*128 + r)*128 + koff + seg);
      *(uint4*)(&Bl[r*LDA + seg]) = v;
    }
    __syncthreads();
    #pragma unroll
    for(int ks=0; ks<2; ks++){
      bf16x8 a[4], b[4];
      #pragma unroll
      for(int f=0; f<4; f++){
        a[f] = *(const bf16x8*)&Al[(wr*64 + f*16 + lm)*LDA + ks*32 + kg*8];
        b[f] = *(const bf16x8*)&Bl[(wc*64 + f*16 + lm)*LDA + ks*32 + kg*8];
      }
      #pragma unroll
      for(int fm=0; fm<4; fm++)
        #pragma unroll
        for(int fn=0; fn<4; fn++)
          acc[fm][fn] = __builtin_amdgcn_mfma_f32_16x16x32_bf16(a[fm], b[fn], acc[fm][fn], 0,0,0);
    }
  }
  int crow0 = (lane>>4)*4;
  #pragma unroll
  for(int fm=0; fm<4; fm++){
    #pragma unroll
    for(int fn=0; fn<4; fn++){
      int cc = cb*128 + wc*64 + fn*16 + lm;
      float bv = (cc < 40) ? bias[cc] : 0.f;
      #pragma unroll
      for(int j=0;j<4;j++){
        int row = nbase + wr*64 + fm*16 + crow0 + j;
        if(row < N){
          float v = acc[fm][fn][j] + bv;
          z[(size_t)row*256 + cc] = f2bf(v);
        }
      }
    }
  }
}

// ---------------- host ----------------

extern "C" void kernel_launch(void* const* d_in, const int* in_sizes, int n_in,
                              void* d_out, int out_size, void* d_ws, size_t ws_size,
                              hipStream_t stream){
  const float* x  = (const float*)d_in[0];
  const int*   ei = (const int*)d_in[1];
  const float* w1 = (const float*)d_in[2];
  const float* b1 = (const float*)d_in[3];
  const float* w2 = (const float*)d_in[4];
  const float* b2 = (const float*)d_in[5];
  float* out = (float*)d_out;
  int N = in_sizes[0] / 128;
  int E = in_sizes[1] / 2;
  const int* rowv = ei;
  const int* colv = ei + E;

  char* wsp = (char*)d_ws;
  size_t off = 0;
  auto alloc = [&](size_t bytes)->void*{
    void* p = wsp + off;
    off = (off + bytes + 255) & ~(size_t)255;
    return p;
  };
  int*      deg    = (int*)     alloc((size_t)N*4);
  float*    dis    = (float*)   alloc((size_t)N*4);
  int*      rowptr = (int*)     alloc((size_t)(N+1)*4);
  int*      cur    = (int*)     alloc((size_t)N*4);
  int*      bsums  = (int*)     alloc(512);
  int*      boffs  = (int*)     alloc(512);
  unsigned* ed     = (unsigned*)alloc((size_t)E*4);
  ushort*   xb     = (ushort*)  alloc((size_t)N*128*2);
  ushort*   hb1    = (ushort*)  alloc((size_t)N*128*2);
  ushort*   hb2    = (ushort*)  alloc((size_t)N*128*2);
  ushort*   hb3    = (ushort*)  alloc((size_t)N*128*2);
  ushort*   out1b  = (ushort*)  alloc((size_t)N*128*2);
  ushort*   w1t    = (ushort*)  alloc(128*512*2);
  ushort*   w2t    = (ushort*)  alloc(256*128*2);
  ushort*   zst    = (ushort*)  alloc((size_t)N*256*2);
  ushort*   ta     = hb1;   // dead after k_gemm1
  ushort*   tb     = hb2;
  (void)ws_size;

  int eb = (E+255)/256;
  int nb = (N+SCHUNK-1)/SCHUNK;

  hipMemsetAsync(deg, 0, (size_t)N*4, stream);
  k_count <<<eb, 256, 0, stream>>>(colv, deg, E);
  k_dis   <<<(N+255)/256, 256, 0, stream>>>(deg, dis, N);
  k_scan_a<<<nb, SBS, 0, stream>>>(deg, bsums, N);
  k_scan_b<<<1, 64, 0, stream>>>(bsums, boffs, rowptr, nb, N);
  k_scan_c<<<nb, SBS, 0, stream>>>(deg, boffs, rowptr, cur, N);
  k_fill  <<<eb, 256, 0, stream>>>(rowv, colv, cur, ed, E);

  k_cast_x <<<(N*32+255)/256, 256, 0, stream>>>(x, xb, N*32);
  k_castw1 <<<256, 256, 0, stream>>>(w1, w1t);
  k_castw2 <<<128, 256, 0, stream>>>(w2, w2t);

  int sg = (N+3)/4;
  int gb = (N+127)/128;
  // layer 1: propagate width-128 (true-space, weights split dis[r] x dis[c])
  k_spmm1<<<sg, 256, 0, stream>>>(xb,  hb1, rowptr, ed, dis, N);
  k_spmm1<<<sg, 256, 0, stream>>>(hb1, hb2, rowptr, ed, dis, N);
  k_spmm1<<<sg, 256, 0, stream>>>(hb2, hb3, rowptr, ed, dis, N);
  k_gemm1<<<gb, 256, 0, stream>>>(xb, hb1, hb2, hb3, w1t, b1, out1b, N);
  // layer 2: z_k = H @ W2_k, then Horner propagation at width 64
  k_gemm2<<<dim3(gb,2), 256, 0, stream>>>(out1b, w2t, b2, zst, N);
  k_spmm2    <<<sg, 256, 0, stream>>>(zst+192, 256, zst+128, 256, ta, rowptr, ed, dis, N);
  k_spmm2    <<<sg, 256, 0, stream>>>(ta,       64, zst+64,  256, tb, rowptr, ed, dis, N);
  k_spmm2_lsm<<<sg, 256, 0, stream>>>(tb,       64, zst,     256, out, rowptr, ed, dis, N);
}

// Round 7
// 565.788 us; speedup vs baseline: 1.1647x; 1.1647x over previous
//
#include <hip/hip_runtime.h>
#include <math.h>

typedef __bf16 bf16x8 __attribute__((ext_vector_type(8)));
typedef float  f32x4  __attribute__((ext_vector_type(4)));

__device__ __forceinline__ unsigned short f2bf(float f){
  unsigned u = __float_as_uint(f);
  unsigned r = (u + 0x7fffu + ((u>>16)&1u)) >> 16;
  return (unsigned short)r;
}
__device__ __forceinline__ float bflo(unsigned v){ return __uint_as_float(v<<16); }
__device__ __forceinline__ float bfhi(unsigned v){ return __uint_as_float(v & 0xffff0000u); }

// ---------------- degree + dis ----------------

__global__ void k_count(const int* __restrict__ col, int* __restrict__ deg, int E){
  int e = blockIdx.x*256 + threadIdx.x;
  if(e < E) atomicAdd(&deg[col[e]], 1);
}

__global__ void k_dis(const int* __restrict__ deg, float* __restrict__ dis, int N){
  int i = blockIdx.x*256 + threadIdx.x;
  if(i < N){ int d = deg[i]; dis[i] = d > 0 ? rsqrtf((float)d) : 0.f; }
}

// ---------------- bucket counts (256-node buckets) ----------------

__global__ void __launch_bounds__(256) k_bsum(const int* __restrict__ deg,
                                              int* __restrict__ hcnt, int N){
  __shared__ int ls[4];
  int b = blockIdx.x, tid = threadIdx.x;
  int i = (b<<8) + tid;
  int s = (i<N) ? deg[i] : 0;
  #pragma unroll
  for(int o=32;o>0;o>>=1) s += __shfl_down(s,o);
  int lane = tid & 63, w = tid >> 6;
  if(lane==0) ls[w]=s;
  __syncthreads();
  if(tid==0) hcnt[b] = ls[0]+ls[1]+ls[2]+ls[3];
}

// single block: scan hcnt[NB] -> bbase[NB+1], init gcur, rowptr[N]=E
__global__ void __launch_bounds__(512) k_bscan(const int* __restrict__ hcnt,
                                               int* __restrict__ bbase, int* __restrict__ gcur,
                                               int* __restrict__ rowptr, int NB, int N){
  __shared__ int ts[512];
  int tid = threadIdx.x;
  int v = (tid<NB) ? hcnt[tid] : 0;
  ts[tid]=v; __syncthreads();
  for(int o=1;o<512;o<<=1){
    int t=(tid>=o)?ts[tid-o]:0; __syncthreads();
    ts[tid]+=t; __syncthreads();
  }
  int ex = ts[tid]-v;            // exclusive
  if(tid<=NB) bbase[tid] = (tid<NB) ? ex : ts[NB-1];
  if(tid<NB)  gcur[tid]  = ex;
  if(tid==0)  rowptr[N]  = ts[511];   // == E
}

// ---------------- partition into buckets: part[pos] = {src, col} ----------------

#define PT 4096

__global__ void __launch_bounds__(256) k_part(const int* __restrict__ rowv,
                                              const int* __restrict__ colv,
                                              int* __restrict__ gcur,
                                              uint2* __restrict__ part, int E){
  __shared__ int lh[512];
  __shared__ int lb[512];
  int tid = threadIdx.x;
  for(int i=tid;i<512;i+=256) lh[i]=0;
  __syncthreads();
  int base = blockIdx.x*PT;
  int bmax = E - base; if(bmax > PT) bmax = PT;
  for(int k=tid;k<bmax;k+=256){
    int c = colv[base+k];
    atomicAdd(&lh[c>>8],1);
  }
  __syncthreads();
  for(int i=tid;i<512;i+=256){
    int cnt = lh[i];
    lb[i] = cnt>0 ? atomicAdd(&gcur[i],cnt) : 0;
  }
  __syncthreads();
  for(int i=tid;i<512;i+=256) lh[i]=0;
  __syncthreads();
  for(int k=tid;k<bmax;k+=256){
    int r = rowv[base+k], c = colv[base+k];
    int b = c>>8;
    int pos = lb[b] + atomicAdd(&lh[b],1);
    part[pos] = make_uint2((unsigned)r,(unsigned)c);
  }
}

// ---------------- per-bucket exact counting sort -> ed {src,w}, rowptr ----------------

#define CAP 6144

__global__ void __launch_bounds__(256) k_csort(const uint2* __restrict__ part,
                                               const int* __restrict__ bbase,
                                               const float* __restrict__ dis,
                                               uint2* __restrict__ ed,
                                               int* __restrict__ rowptr, int N){
  __shared__ uint2 st[CAP];
  __shared__ int cnt[256];
  __shared__ int ts[256];
  int b = blockIdx.x, tid = threadIdx.x;
  int nb0 = b<<8;
  int g0 = bbase[b], g1 = bbase[b+1];
  int ce = g1-g0;
  cnt[tid]=0; __syncthreads();
  for(int i=tid;i<ce;i+=256){
    int cl = (int)part[g0+i].y - nb0;
    atomicAdd(&cnt[cl],1);
  }
  __syncthreads();
  int v = cnt[tid]; ts[tid]=v; __syncthreads();
  for(int o=1;o<256;o<<=1){
    int t=(tid>=o)?ts[tid-o]:0; __syncthreads();
    ts[tid]+=t; __syncthreads();
  }
  int ex = ts[tid]-v;
  int node = nb0+tid;
  if(node < N) rowptr[node] = g0 + ex;
  cnt[tid] = ex;   // reuse as cursor
  __syncthreads();
  for(int i=tid;i<ce;i+=256){
    uint2 pc = part[g0+i];
    int cl = (int)pc.y - nb0;
    float w = dis[pc.x]*dis[pc.y];
    int pos = atomicAdd(&cnt[cl],1);
    if(pos < CAP) st[pos] = make_uint2(pc.x, __float_as_uint(w));
  }
  __syncthreads();
  for(int i=tid;i<ce;i+=256) ed[g0+i] = st[i];
}

// ---------------- casts ----------------

__global__ void k_cast_x(const float* __restrict__ x, ushort* __restrict__ xb, int n4){
  int t = blockIdx.x*256 + threadIdx.x;
  if(t < n4){
    float4 v = ((const float4*)x)[t];
    uint2 o;
    o.x = (unsigned)f2bf(v.x) | ((unsigned)f2bf(v.y)<<16);
    o.y = (unsigned)f2bf(v.z) | ((unsigned)f2bf(v.w)<<16);
    ((uint2*)xb)[t] = o;
  }
}

__global__ void k_castw1(const float* __restrict__ w1, ushort* __restrict__ w1t){
  int i = blockIdx.x*256 + threadIdx.x;   // 65536
  int n = i & 127, kin = (i>>7)&127, s = i>>14;
  w1t[n*512 + s*128 + kin] = f2bf(w1[i]);
}

__global__ void k_castw2(const float* __restrict__ w2, ushort* __restrict__ w2t){
  int i = blockIdx.x*256 + threadIdx.x;   // 32768
  int k = i & 127, np = i>>7;
  int s = np>>6, nn = np&63;
  float v = (nn<40) ? w2[(s*128 + k)*40 + nn] : 0.f;
  w2t[i] = f2bf(v);
}

// ------- SpMM width-128 bf16: dst[n] = sum w*src[r]; 4 edges in flight -------

__global__ void __launch_bounds__(256) k_spmm1(
    const ushort* __restrict__ src, ushort* __restrict__ dst,
    const int* __restrict__ rowptr, const uint2* __restrict__ ed, int N){
  int wid = threadIdx.x>>6, lane = threadIdx.x&63;
  int n = blockIdx.x*4 + wid;
  if(n>=N) return;
  int p = lane>>4, c = lane&15;
  int s = rowptr[n], e = rowptr[n+1];
  float a[8];
  #pragma unroll
  for(int i=0;i<8;i++) a[i]=0.f;
  for(int b=s; b<e; b+=64){
    int m = e-b; if(m>64) m=64;
    uint2 eD = make_uint2(0u,0u);
    if(lane<m) eD = ed[b+lane];
    int tmax = (m+3)>>2;
    for(int t=0;t<tmax;t++){
      int j = 4*t + p;
      int r = __shfl((int)eD.x, j);
      float wg = __uint_as_float(__shfl((int)eD.y, j));
      uint4 v = *(const uint4*)(src + (size_t)r*128 + c*8);
      a[0]+=wg*bflo(v.x); a[1]+=wg*bfhi(v.x);
      a[2]+=wg*bflo(v.y); a[3]+=wg*bfhi(v.y);
      a[4]+=wg*bflo(v.z); a[5]+=wg*bfhi(v.z);
      a[6]+=wg*bflo(v.w); a[7]+=wg*bfhi(v.w);
    }
  }
  #pragma unroll
  for(int i=0;i<8;i++){ a[i]+=__shfl_xor(a[i],32); a[i]+=__shfl_xor(a[i],16); }
  if(p==0){
    uint4 o;
    o.x = (unsigned)f2bf(a[0]) | ((unsigned)f2bf(a[1])<<16);
    o.y = (unsigned)f2bf(a[2]) | ((unsigned)f2bf(a[3])<<16);
    o.z = (unsigned)f2bf(a[4]) | ((unsigned)f2bf(a[5])<<16);
    o.w = (unsigned)f2bf(a[6]) | ((unsigned)f2bf(a[7])<<16);
    *(uint4*)(dst + (size_t)n*128 + c*8) = o;
  }
}

// ------- SpMM width-64 + add z: 8 edges in flight -------

__global__ void __launch_bounds__(256) k_spmm2(
    const ushort* __restrict__ tprev, int ss,
    const ushort* __restrict__ z, int zs,
    ushort* __restrict__ tnew,
    const int* __restrict__ rowptr, const uint2* __restrict__ ed, int N){
  int wid = threadIdx.x>>6, lane = threadIdx.x&63;
  int n = blockIdx.x*4 + wid;
  if(n>=N) return;
  int p = lane>>3, c = lane&7;
  int s = rowptr[n], e = rowptr[n+1];
  float a[8];
  #pragma unroll
  for(int i=0;i<8;i++) a[i]=0.f;
  for(int b=s; b<e; b+=64){
    int m = e-b; if(m>64) m=64;
    uint2 eD = make_uint2(0u,0u);
    if(lane<m) eD = ed[b+lane];
    int tmax = (m+7)>>3;
    for(int t=0;t<tmax;t++){
      int j = 8*t + p;
      int r = __shfl((int)eD.x, j);
      float wg = __uint_as_float(__shfl((int)eD.y, j));
      uint4 v = *(const uint4*)(tprev + (size_t)r*ss + c*8);
      a[0]+=wg*bflo(v.x); a[1]+=wg*bfhi(v.x);
      a[2]+=wg*bflo(v.y); a[3]+=wg*bfhi(v.y);
      a[4]+=wg*bflo(v.z); a[5]+=wg*bfhi(v.z);
      a[6]+=wg*bflo(v.w); a[7]+=wg*bfhi(v.w);
    }
  }
  #pragma unroll
  for(int i=0;i<8;i++){ a[i]+=__shfl_xor(a[i],32); a[i]+=__shfl_xor(a[i],16); a[i]+=__shfl_xor(a[i],8); }
  if(lane<8){
    uint4 vz = *(const uint4*)(z + (size_t)n*zs + c*8);
    a[0]+=bflo(vz.x); a[1]+=bfhi(vz.x);
    a[2]+=bflo(vz.y); a[3]+=bfhi(vz.y);
    a[4]+=bflo(vz.z); a[5]+=bfhi(vz.z);
    a[6]+=bflo(vz.w); a[7]+=bfhi(vz.w);
    uint4 o;
    o.x = (unsigned)f2bf(a[0]) | ((unsigned)f2bf(a[1])<<16);
    o.y = (unsigned)f2bf(a[2]) | ((unsigned)f2bf(a[3])<<16);
    o.z = (unsigned)f2bf(a[4]) | ((unsigned)f2bf(a[5])<<16);
    o.w = (unsigned)f2bf(a[6]) | ((unsigned)f2bf(a[7])<<16);
    *(uint4*)(tnew + (size_t)n*64 + c*8) = o;
  }
}

// Final: out = log_softmax(A*tprev + z0) cols 0..39, f32 [N][40]

__global__ void __launch_bounds__(256) k_spmm2_lsm(
    const ushort* __restrict__ tprev, int ss,
    const ushort* __restrict__ z, int zs,
    float* __restrict__ out,
    const int* __restrict__ rowptr, const uint2* __restrict__ ed, int N){
  int wid = threadIdx.x>>6, lane = threadIdx.x&63;
  int n = blockIdx.x*4 + wid;
  if(n>=N) return;
  int p = lane>>3, c = lane&7;
  int s = rowptr[n], e = rowptr[n+1];
  float a[8];
  #pragma unroll
  for(int i=0;i<8;i++) a[i]=0.f;
  for(int b=s; b<e; b+=64){
    int m = e-b; if(m>64) m=64;
    uint2 eD = make_uint2(0u,0u);
    if(lane<m) eD = ed[b+lane];
    int tmax = (m+7)>>3;
    for(int t=0;t<tmax;t++){
      int j = 8*t + p;
      int r = __shfl((int)eD.x, j);
      float wg = __uint_as_float(__shfl((int)eD.y, j));
      uint4 v = *(const uint4*)(tprev + (size_t)r*ss + c*8);
      a[0]+=wg*bflo(v.x); a[1]+=wg*bfhi(v.x);
      a[2]+=wg*bflo(v.y); a[3]+=wg*bfhi(v.y);
      a[4]+=wg*bflo(v.z); a[5]+=wg*bfhi(v.z);
      a[6]+=wg*bflo(v.w); a[7]+=wg*bfhi(v.w);
    }
  }
  #pragma unroll
  for(int i=0;i<8;i++){ a[i]+=__shfl_xor(a[i],32); a[i]+=__shfl_xor(a[i],16); a[i]+=__shfl_xor(a[i],8); }
  uint4 vz = *(const uint4*)(z + (size_t)n*zs + c*8);
  a[0]+=bflo(vz.x); a[1]+=bfhi(vz.x);
  a[2]+=bflo(vz.y); a[3]+=bfhi(vz.y);
  a[4]+=bflo(vz.z); a[5]+=bfhi(vz.z);
  a[6]+=bflo(vz.w); a[7]+=bfhi(vz.w);
  bool valid = (c < 5);
  float mx = -1e30f;
  #pragma unroll
  for(int i=0;i<8;i++) if(valid) mx = fmaxf(mx, a[i]);
  #pragma unroll
  for(int o=1;o<8;o<<=1) mx = fmaxf(mx, __shfl_xor(mx, o));
  float sum = 0.f;
  #pragma unroll
  for(int i=0;i<8;i++) if(valid) sum += expf(a[i]-mx);
  #pragma unroll
  for(int o=1;o<8;o<<=1) sum += __shfl_xor(sum, o);
  float l = mx + logf(sum);
  if(lane<8 && valid){
    float4 o0, o1;
    o0.x=a[0]-l; o0.y=a[1]-l; o0.z=a[2]-l; o0.w=a[3]-l;
    o1.x=a[4]-l; o1.y=a[5]-l; o1.z=a[6]-l; o1.w=a[7]-l;
    float* op = out + (size_t)n*40 + c*8;
    *(float4*)op = o0;
    *(float4*)(op+4) = o1;
  }
}

// ---------------- MFMA GEMM layer 1 ----------------

#define LDA 72

__global__ void __launch_bounds__(256) k_gemm1(
    const ushort* __restrict__ xb, const ushort* __restrict__ h1,
    const ushort* __restrict__ h2, const ushort* __restrict__ h3,
    const ushort* __restrict__ w1t, const float* __restrict__ bias,
    ushort* __restrict__ outb, int N){
  __shared__ ushort Al[128*LDA];
  __shared__ ushort Bl[128*LDA];
  int tid = threadIdx.x;
  int wid = tid>>6, lane = tid&63;
  int wr = wid>>1, wc = wid&1;
  int lm = lane&15, kg = lane>>4;
  int nbase = blockIdx.x*128;
  f32x4 acc[4][4];
  #pragma unroll
  for(int i=0;i<4;i++)
    #pragma unroll
    for(int j=0;j<4;j++) acc[i][j] = (f32x4){0.f,0.f,0.f,0.f};

  for(int kc=0; kc<8; kc++){
    const ushort* asrc = (kc<2) ? xb : (kc<4) ? h1 : (kc<6) ? h2 : h3;
    int koff = (kc&1)*64;
    __syncthreads();
    #pragma unroll
    for(int i=0;i<4;i++){
      int slot = tid + i*256;
      int r = slot>>3, seg = (slot&7)*8;
      int n = nbase + r;
      uint4 v = make_uint4(0,0,0,0);
      if(n < N) v = *(const uint4*)(asrc + (size_t)n*128 + koff + seg);
      *(uint4*)(&Al[r*LDA + seg]) = v;
    }
    #pragma unroll
    for(int i=0;i<4;i++){
      int slot = tid + i*256;
      int r = slot>>3, seg = (slot&7)*8;
      uint4 v = *(const uint4*)(w1t + (size_t)r*512 + kc*64 + seg);
      *(uint4*)(&Bl[r*LDA + seg]) = v;
    }
    __syncthreads();
    #pragma unroll
    for(int ks=0; ks<2; ks++){
      bf16x8 a[4], b[4];
      #pragma unroll
      for(int f=0; f<4; f++){
        a[f] = *(const bf16x8*)&Al[(wr*64 + f*16 + lm)*LDA + ks*32 + kg*8];
        b[f] = *(const bf16x8*)&Bl[(wc*64 + f*16 + lm)*LDA + ks*32 + kg*8];
      }
      #pragma unroll
      for(int fm=0; fm<4; fm++)
        #pragma unroll
        for(int fn=0; fn<4; fn++)
          acc[fm][fn] = __builtin_amdgcn_mfma_f32_16x16x32_bf16(a[fm], b[fn], acc[fm][fn], 0,0,0);
    }
  }
  int crow0 = (lane>>4)*4;
  #pragma unroll
  for(int fm=0; fm<4; fm++){
    #pragma unroll
    for(int fn=0; fn<4; fn++){
      int col = wc*64 + fn*16 + lm;
      float bv = bias[col];
      #pragma unroll
      for(int j=0;j<4;j++){
        int row = nbase + wr*64 + fm*16 + crow0 + j;
        if(row < N){
          float v = fmaxf(acc[fm][fn][j] + bv, 0.f);
          outb[(size_t)row*128 + col] = f2bf(v);
        }
      }
    }
  }
}

// ------- MFMA GEMM layer 2: zstack[N][256] = out1b @ W2t^T (+b2 on cols<40) -------

__global__ void __launch_bounds__(256) k_gemm2(
    const ushort* __restrict__ ab, const ushort* __restrict__ w2t,
    const float* __restrict__ bias, ushort* __restrict__ z, int N){
  __shared__ ushort Al[128*LDA];
  __shared__ ushort Bl[128*LDA];
  int tid = threadIdx.x;
  int wid = tid>>6, lane = tid&63;
  int wr = wid>>1, wc = wid&1;
  int lm = lane&15, kg = lane>>4;
  int nbase = blockIdx.x*128;
  int cb = blockIdx.y;
  f32x4 acc[4][4];
  #pragma unroll
  for(int i=0;i<4;i++)
    #pragma unroll
    for(int j=0;j<4;j++) acc[i][j] = (f32x4){0.f,0.f,0.f,0.f};

  for(int kc=0; kc<2; kc++){
    int koff = kc*64;
    __syncthreads();
    #pragma unroll
    for(int i=0;i<4;i++){
      int slot = tid + i*256;
      int r = slot>>3, seg = (slot&7)*8;
      int n = nbase + r;
      uint4 v = make_uint4(0,0,0,0);
      if(n < N) v = *(const uint4*)(ab + (size_t)n*128 + koff + seg);
      *(uint4*)(&Al[r*LDA + seg]) = v;
    }
    #pragma unroll
    for(int i=0;i<4;i++){
      int slot = tid + i*256;
      int r = slot>>3, seg = (slot&7)*8;
      uint4 v = *(const uint4*)(w2t + (size_t)(cb*128 + r)*128 + koff + seg);
      *(uint4*)(&Bl[r*LDA + seg]) = v;
    }
    __syncthreads();
    #pragma unroll
    for(int ks=0; ks<2; ks++){
      bf16x8 a[4], b[4];
      #pragma unroll
      for(int f=0; f<4; f++){
        a[f] = *(const bf16x8*)&Al[(wr*64 + f*16 + lm)*LDA + ks*32 + kg*8];
        b[f] = *(const bf16x8*)&Bl[(wc*64 + f*16 + lm)*LDA + ks*32 + kg*8];
      }
      #pragma unroll
      for(int fm=0; fm<4; fm++)
        #pragma unroll
        for(int fn=0; fn<4; fn++)
          acc[fm][fn] = __builtin_amdgcn_mfma_f32_16x16x32_bf16(a[fm], b[fn], acc[fm][fn], 0,0,0);
    }
  }
  int crow0 = (lane>>4)*4;
  #pragma unroll
  for(int fm=0; fm<4; fm++){
    #pragma unroll
    for(int fn=0; fn<4; fn++){
      int cc = cb*128 + wc*64 + fn*16 + lm;
      float bv = (cc < 40) ? bias[cc] : 0.f;
      #pragma unroll
      for(int j=0;j<4;j++){
        int row = nbase + wr*64 + fm*16 + crow0 + j;
        if(row < N){
          float v = acc[fm][fn][j] + bv;
          z[(size_t)row*256 + cc] = f2bf(v);
        }
      }
    }
  }
}

// ---------------- host ----------------

extern "C" void kernel_launch(void* const* d_in, const int* in_sizes, int n_in,
                              void* d_out, int out_size, void* d_ws, size_t ws_size,
                              hipStream_t stream){
  const float* x  = (const float*)d_in[0];
  const int*   ei = (const int*)d_in[1];
  const float* w1 = (const float*)d_in[2];
  const float* b1 = (const float*)d_in[3];
  const float* w2 = (const float*)d_in[4];
  const float* b2 = (const float*)d_in[5];
  float* out = (float*)d_out;
  int N = in_sizes[0] / 128;
  int E = in_sizes[1] / 2;
  const int* rowv = ei;
  const int* colv = ei + E;
  int NB = (N + 255) >> 8;

  char* wsp = (char*)d_ws;
  size_t off = 0;
  auto alloc = [&](size_t bytes)->void*{
    void* p = wsp + off;
    off = (off + bytes + 255) & ~(size_t)255;
    return p;
  };
  int*      deg    = (int*)     alloc((size_t)N*4);
  float*    dis    = (float*)   alloc((size_t)N*4);
  int*      rowptr = (int*)     alloc((size_t)(N+1)*4);
  int*      hcnt   = (int*)     alloc(512*4);
  int*      bbase  = (int*)     alloc(513*4);
  int*      gcur   = (int*)     alloc(512*4);
  uint2*    part   = (uint2*)   alloc((size_t)E*8);
  uint2*    ed     = (uint2*)   alloc((size_t)E*8);
  ushort*   xb     = (ushort*)  alloc((size_t)N*128*2);
  ushort*   hb1    = (ushort*)  alloc((size_t)N*128*2);
  ushort*   hb2    = (ushort*)  alloc((size_t)N*128*2);
  ushort*   hb3    = (ushort*)  alloc((size_t)N*128*2);
  ushort*   out1b  = (ushort*)  alloc((size_t)N*128*2);
  ushort*   w1t    = (ushort*)  alloc(128*512*2);
  ushort*   w2t    = (ushort*)  alloc(256*128*2);
  ushort*   zst    = (ushort*)  alloc((size_t)N*256*2);
  ushort*   ta     = hb1;   // dead after k_gemm1
  ushort*   tb     = hb2;
  (void)ws_size;

  int eb = (E+255)/256;

  hipMemsetAsync(deg, 0, (size_t)N*4, stream);
  k_count <<<eb, 256, 0, stream>>>(colv, deg, E);
  k_dis   <<<(N+255)/256, 256, 0, stream>>>(deg, dis, N);
  k_bsum  <<<NB, 256, 0, stream>>>(deg, hcnt, N);
  k_bscan <<<1, 512, 0, stream>>>(hcnt, bbase, gcur, rowptr, NB, N);
  k_part  <<<(E+PT-1)/PT, 256, 0, stream>>>(rowv, colv, gcur, part, E);
  k_csort <<<NB, 256, 0, stream>>>(part, bbase, dis, ed, rowptr, N);

  k_cast_x <<<(N*32+255)/256, 256, 0, stream>>>(x, xb, N*32);
  k_castw1 <<<256, 256, 0, stream>>>(w1, w1t);
  k_castw2 <<<128, 256, 0, stream>>>(w2, w2t);

  int sg = (N+3)/4;
  int gb = (N+127)/128;
  // layer 1: propagate width-128 bf16
  k_spmm1<<<sg, 256, 0, stream>>>(xb,  hb1, rowptr, ed, N);
  k_spmm1<<<sg, 256, 0, stream>>>(hb1, hb2, rowptr, ed, N);
  k_spmm1<<<sg, 256, 0, stream>>>(hb2, hb3, rowptr, ed, N);
  k_gemm1<<<gb, 256, 0, stream>>>(xb, hb1, hb2, hb3, w1t, b1, out1b, N);
  // layer 2: z_k = H @ W2_k, then Horner propagation at width 64
  k_gemm2<<<dim3(gb,2), 256, 0, stream>>>(out1b, w2t, b2, zst, N);
  k_spmm2    <<<sg, 256, 0, stream>>>(zst+192, 256, zst+128, 256, ta, rowptr, ed, N);
  k_spmm2    <<<sg, 256, 0, stream>>>(ta,       64, zst+64,  256, tb, rowptr, ed, N);
  k_spmm2_lsm<<<sg, 256, 0, stream>>>(tb,       64, zst,     256, out, rowptr, ed, N);
}

// Round 8
// 515.726 us; speedup vs baseline: 1.2778x; 1.0971x over previous
//
#include <hip/hip_runtime.h>
#include <math.h>

typedef __bf16 bf16x8 __attribute__((ext_vector_type(8)));
typedef float  f32x4  __attribute__((ext_vector_type(4)));

__device__ __forceinline__ unsigned short f2bf(float f){
  unsigned u = __float_as_uint(f);
  unsigned r = (u + 0x7fffu + ((u>>16)&1u)) >> 16;
  return (unsigned short)r;
}
__device__ __forceinline__ float bflo(unsigned v){ return __uint_as_float(v<<16); }
__device__ __forceinline__ float bfhi(unsigned v){ return __uint_as_float(v & 0xffff0000u); }

// ---------------- bucket histogram (256-node buckets), replaces k_count/k_bsum ----------------

#define PT 4096

__global__ void __launch_bounds__(256) k_phist(const int* __restrict__ colv,
                                               int* __restrict__ hcnt, int E){
  __shared__ int lh[512];
  int tid = threadIdx.x;
  for(int i=tid;i<512;i+=256) lh[i]=0;
  __syncthreads();
  int base = blockIdx.x*PT;
  int bmax = E - base; if(bmax > PT) bmax = PT;
  for(int k=tid;k<bmax;k+=256){
    int c = colv[base+k];
    atomicAdd(&lh[c>>8],1);
  }
  __syncthreads();
  for(int i=tid;i<512;i+=256){
    int cnt = lh[i];
    if(cnt>0) atomicAdd(&hcnt[i],cnt);
  }
}

// single block: scan hcnt -> bbase[513], init gcur, rowptr[N]=E
__global__ void __launch_bounds__(512) k_bscan(const int* __restrict__ hcnt,
                                               int* __restrict__ bbase, int* __restrict__ gcur,
                                               int* __restrict__ rowptr, int NB, int N){
  __shared__ int ts[512];
  int tid = threadIdx.x;
  int v = (tid<NB) ? hcnt[tid] : 0;
  ts[tid]=v; __syncthreads();
  for(int o=1;o<512;o<<=1){
    int t=(tid>=o)?ts[tid-o]:0; __syncthreads();
    ts[tid]+=t; __syncthreads();
  }
  int ex = ts[tid]-v;            // exclusive
  if(tid<=NB) bbase[tid] = (tid<NB) ? ex : ts[NB-1];
  if(tid<NB)  gcur[tid]  = ex;
  if(tid==0)  rowptr[N]  = ts[511];   // == E
}

// ---------------- partition into buckets: part[pos] = (colLow8<<24) | src ----------------

__global__ void __launch_bounds__(256) k_part(const int* __restrict__ rowv,
                                              const int* __restrict__ colv,
                                              int* __restrict__ gcur,
                                              unsigned* __restrict__ part, int E){
  __shared__ int lh[512];
  __shared__ int lb[512];
  int tid = threadIdx.x;
  for(int i=tid;i<512;i+=256) lh[i]=0;
  __syncthreads();
  int base = blockIdx.x*PT;
  int bmax = E - base; if(bmax > PT) bmax = PT;
  for(int k=tid;k<bmax;k+=256){
    int c = colv[base+k];
    atomicAdd(&lh[c>>8],1);
  }
  __syncthreads();
  for(int i=tid;i<512;i+=256){
    int cnt = lh[i];
    lb[i] = cnt>0 ? atomicAdd(&gcur[i],cnt) : 0;
  }
  __syncthreads();
  for(int i=tid;i<512;i+=256) lh[i]=0;
  __syncthreads();
  for(int k=tid;k<bmax;k+=256){
    int r = rowv[base+k], c = colv[base+k];
    int b = c>>8;
    int pos = lb[b] + atomicAdd(&lh[b],1);
    part[pos] = ((unsigned)(c&255)<<24) | (unsigned)r;
  }
}

// ------- per-bucket counting sort -> ed4 (src), rowptr, dis (deg from counts) -------

#define CAP 6144

__global__ void __launch_bounds__(256) k_csort(const unsigned* __restrict__ part,
                                               const int* __restrict__ bbase,
                                               float* __restrict__ dis,
                                               unsigned* __restrict__ ed4,
                                               int* __restrict__ rowptr, int N){
  __shared__ unsigned st[CAP];
  __shared__ int cnt[256];
  __shared__ int ts[256];
  int b = blockIdx.x, tid = threadIdx.x;
  int nb0 = b<<8;
  int g0 = bbase[b], g1 = bbase[b+1];
  int ce = g1-g0;
  cnt[tid]=0; __syncthreads();
  for(int i=tid;i<ce;i+=256){
    atomicAdd(&cnt[part[g0+i]>>24],1);
  }
  __syncthreads();
  int v = cnt[tid];              // in-degree of node nb0+tid
  ts[tid]=v; __syncthreads();
  for(int o=1;o<256;o<<=1){
    int t=(tid>=o)?ts[tid-o]:0; __syncthreads();
    ts[tid]+=t; __syncthreads();
  }
  int ex = ts[tid]-v;
  int node = nb0+tid;
  if(node < N){
    rowptr[node] = g0 + ex;
    dis[node] = v > 0 ? rsqrtf((float)v) : 0.f;
  }
  cnt[tid] = ex;   // reuse as cursor
  __syncthreads();
  for(int i=tid;i<ce;i+=256){
    unsigned pc = part[g0+i];
    int pos = atomicAdd(&cnt[pc>>24],1);
    if(pos < CAP) st[pos] = pc & 0xFFFFFFu;
  }
  __syncthreads();
  for(int i=tid;i<ce;i+=256) ed4[g0+i] = st[i];
}

// ------- weight fill: ed8[e] = {src, dis[src]*dis[n]} , coalesced -------

__global__ void __launch_bounds__(256) k_wfill(const unsigned* __restrict__ ed4,
                                               const int* __restrict__ rowptr,
                                               const float* __restrict__ dis,
                                               uint2* __restrict__ ed8, int N){
  int wid = threadIdx.x>>6, lane = threadIdx.x&63;
  int n = blockIdx.x*4 + wid;
  if(n>=N) return;
  int s = rowptr[n], e = rowptr[n+1];
  float dc = dis[n];
  for(int i=s+lane; i<e; i+=64){
    unsigned r = ed4[i];
    ed8[i] = make_uint2(r, __float_as_uint(dis[r]*dc));
  }
}

// ---------------- casts ----------------

__global__ void k_cast_x(const float* __restrict__ x, ushort* __restrict__ xb, int n4){
  int t = blockIdx.x*256 + threadIdx.x;
  if(t < n4){
    float4 v = ((const float4*)x)[t];
    uint2 o;
    o.x = (unsigned)f2bf(v.x) | ((unsigned)f2bf(v.y)<<16);
    o.y = (unsigned)f2bf(v.z) | ((unsigned)f2bf(v.w)<<16);
    ((uint2*)xb)[t] = o;
  }
}

__global__ void k_castw1(const float* __restrict__ w1, ushort* __restrict__ w1t){
  int i = blockIdx.x*256 + threadIdx.x;   // 65536
  int n = i & 127, kin = (i>>7)&127, s = i>>14;
  w1t[n*512 + s*128 + kin] = f2bf(w1[i]);
}

__global__ void k_castw2(const float* __restrict__ w2, ushort* __restrict__ w2t){
  int i = blockIdx.x*256 + threadIdx.x;   // 32768
  int k = i & 127, np = i>>7;
  int s = np>>6, nn = np&63;
  float v = (nn<40) ? w2[(s*128 + k)*40 + nn] : 0.f;
  w2t[i] = f2bf(v);
}

// ------- SpMM width-128 bf16: dst[n] = sum w*src[r]; 4 edges in flight -------

__global__ void __launch_bounds__(256) k_spmm1(
    const ushort* __restrict__ src, ushort* __restrict__ dst,
    const int* __restrict__ rowptr, const uint2* __restrict__ ed, int N){
  int wid = threadIdx.x>>6, lane = threadIdx.x&63;
  int n = blockIdx.x*4 + wid;
  if(n>=N) return;
  int p = lane>>4, c = lane&15;
  int s = rowptr[n], e = rowptr[n+1];
  float a[8];
  #pragma unroll
  for(int i=0;i<8;i++) a[i]=0.f;
  for(int b=s; b<e; b+=64){
    int m = e-b; if(m>64) m=64;
    uint2 eD = make_uint2(0u,0u);
    if(lane<m) eD = ed[b+lane];
    int tmax = (m+3)>>2;
    for(int t=0;t<tmax;t++){
      int j = 4*t + p;
      int r = __shfl((int)eD.x, j);
      float wg = __uint_as_float(__shfl((int)eD.y, j));
      uint4 v = *(const uint4*)(src + (size_t)r*128 + c*8);
      a[0]+=wg*bflo(v.x); a[1]+=wg*bfhi(v.x);
      a[2]+=wg*bflo(v.y); a[3]+=wg*bfhi(v.y);
      a[4]+=wg*bflo(v.z); a[5]+=wg*bfhi(v.z);
      a[6]+=wg*bflo(v.w); a[7]+=wg*bfhi(v.w);
    }
  }
  #pragma unroll
  for(int i=0;i<8;i++){ a[i]+=__shfl_xor(a[i],32); a[i]+=__shfl_xor(a[i],16); }
  if(p==0){
    uint4 o;
    o.x = (unsigned)f2bf(a[0]) | ((unsigned)f2bf(a[1])<<16);
    o.y = (unsigned)f2bf(a[2]) | ((unsigned)f2bf(a[3])<<16);
    o.z = (unsigned)f2bf(a[4]) | ((unsigned)f2bf(a[5])<<16);
    o.w = (unsigned)f2bf(a[6]) | ((unsigned)f2bf(a[7])<<16);
    *(uint4*)(dst + (size_t)n*128 + c*8) = o;
  }
}

// ------- SpMM width-64 + add z: 8 edges in flight -------

__global__ void __launch_bounds__(256) k_spmm2(
    const ushort* __restrict__ tprev, int ss,
    const ushort* __restrict__ z, int zs,
    ushort* __restrict__ tnew,
    const int* __restrict__ rowptr, const uint2* __restrict__ ed, int N){
  int wid = threadIdx.x>>6, lane = threadIdx.x&63;
  int n = blockIdx.x*4 + wid;
  if(n>=N) return;
  int p = lane>>3, c = lane&7;
  int s = rowptr[n], e = rowptr[n+1];
  float a[8];
  #pragma unroll
  for(int i=0;i<8;i++) a[i]=0.f;
  for(int b=s; b<e; b+=64){
    int m = e-b; if(m>64) m=64;
    uint2 eD = make_uint2(0u,0u);
    if(lane<m) eD = ed[b+lane];
    int tmax = (m+7)>>3;
    for(int t=0;t<tmax;t++){
      int j = 8*t + p;
      int r = __shfl((int)eD.x, j);
      float wg = __uint_as_float(__shfl((int)eD.y, j));
      uint4 v = *(const uint4*)(tprev + (size_t)r*ss + c*8);
      a[0]+=wg*bflo(v.x); a[1]+=wg*bfhi(v.x);
      a[2]+=wg*bflo(v.y); a[3]+=wg*bfhi(v.y);
      a[4]+=wg*bflo(v.z); a[5]+=wg*bfhi(v.z);
      a[6]+=wg*bflo(v.w); a[7]+=wg*bfhi(v.w);
    }
  }
  #pragma unroll
  for(int i=0;i<8;i++){ a[i]+=__shfl_xor(a[i],32); a[i]+=__shfl_xor(a[i],16); a[i]+=__shfl_xor(a[i],8); }
  if(lane<8){
    uint4 vz = *(const uint4*)(z + (size_t)n*zs + c*8);
    a[0]+=bflo(vz.x); a[1]+=bfhi(vz.x);
    a[2]+=bflo(vz.y); a[3]+=bfhi(vz.y);
    a[4]+=bflo(vz.z); a[5]+=bfhi(vz.z);
    a[6]+=bflo(vz.w); a[7]+=bfhi(vz.w);
    uint4 o;
    o.x = (unsigned)f2bf(a[0]) | ((unsigned)f2bf(a[1])<<16);
    o.y = (unsigned)f2bf(a[2]) | ((unsigned)f2bf(a[3])<<16);
    o.z = (unsigned)f2bf(a[4]) | ((unsigned)f2bf(a[5])<<16);
    o.w = (unsigned)f2bf(a[6]) | ((unsigned)f2bf(a[7])<<16);
    *(uint4*)(tnew + (size_t)n*64 + c*8) = o;
  }
}

// Final: out = log_softmax(A*tprev + z0) cols 0..39, f32 [N][40]

__global__ void __launch_bounds__(256) k_spmm2_lsm(
    const ushort* __restrict__ tprev, int ss,
    const ushort* __restrict__ z, int zs,
    float* __restrict__ out,
    const int* __restrict__ rowptr, const uint2* __restrict__ ed, int N){
  int wid = threadIdx.x>>6, lane = threadIdx.x&63;
  int n = blockIdx.x*4 + wid;
  if(n>=N) return;
  int p = lane>>3, c = lane&7;
  int s = rowptr[n], e = rowptr[n+1];
  float a[8];
  #pragma unroll
  for(int i=0;i<8;i++) a[i]=0.f;
  for(int b=s; b<e; b+=64){
    int m = e-b; if(m>64) m=64;
    uint2 eD = make_uint2(0u,0u);
    if(lane<m) eD = ed[b+lane];
    int tmax = (m+7)>>3;
    for(int t=0;t<tmax;t++){
      int j = 8*t + p;
      int r = __shfl((int)eD.x, j);
      float wg = __uint_as_float(__shfl((int)eD.y, j));
      uint4 v = *(const uint4*)(tprev + (size_t)r*ss + c*8);
      a[0]+=wg*bflo(v.x); a[1]+=wg*bfhi(v.x);
      a[2]+=wg*bflo(v.y); a[3]+=wg*bfhi(v.y);
      a[4]+=wg*bflo(v.z); a[5]+=wg*bfhi(v.z);
      a[6]+=wg*bflo(v.w); a[7]+=wg*bfhi(v.w);
    }
  }
  #pragma unroll
  for(int i=0;i<8;i++){ a[i]+=__shfl_xor(a[i],32); a[i]+=__shfl_xor(a[i],16); a[i]+=__shfl_xor(a[i],8); }
  uint4 vz = *(const uint4*)(z + (size_t)n*zs + c*8);
  a[0]+=bflo(vz.x); a[1]+=bfhi(vz.x);
  a[2]+=bflo(vz.y); a[3]+=bfhi(vz.y);
  a[4]+=bflo(vz.z); a[5]+=bfhi(vz.z);
  a[6]+=bflo(vz.w); a[7]+=bfhi(vz.w);
  bool valid = (c < 5);
  float mx = -1e30f;
  #pragma unroll
  for(int i=0;i<8;i++) if(valid) mx = fmaxf(mx, a[i]);
  #pragma unroll
  for(int o=1;o<8;o<<=1) mx = fmaxf(mx, __shfl_xor(mx, o));
  float sum = 0.f;
  #pragma unroll
  for(int i=0;i<8;i++) if(valid) sum += expf(a[i]-mx);
  #pragma unroll
  for(int o=1;o<8;o<<=1) sum += __shfl_xor(sum, o);
  float l = mx + logf(sum);
  if(lane<8 && valid){
    float4 o0, o1;
    o0.x=a[0]-l; o0.y=a[1]-l; o0.z=a[2]-l; o0.w=a[3]-l;
    o1.x=a[4]-l; o1.y=a[5]-l; o1.z=a[6]-l; o1.w=a[7]-l;
    float* op = out + (size_t)n*40 + c*8;
    *(float4*)op = o0;
    *(float4*)(op+4) = o1;
  }
}

// ---------------- MFMA GEMM layer 1 ----------------

#define LDA 72

__global__ void __launch_bounds__(256) k_gemm1(
    const ushort* __restrict__ xb, const ushort* __restrict__ h1,
    const ushort* __restrict__ h2, const ushort* __restrict__ h3,
    const ushort* __restrict__ w1t, const float* __restrict__ bias,
    ushort* __restrict__ outb, int N){
  __shared__ ushort Al[128*LDA];
  __shared__ ushort Bl[128*LDA];
  int tid = threadIdx.x;
  int wid = tid>>6, lane = tid&63;
  int wr = wid>>1, wc = wid&1;
  int lm = lane&15, kg = lane>>4;
  int nbase = blockIdx.x*128;
  f32x4 acc[4][4];
  #pragma unroll
  for(int i=0;i<4;i++)
    #pragma unroll
    for(int j=0;j<4;j++) acc[i][j] = (f32x4){0.f,0.f,0.f,0.f};

  for(int kc=0; kc<8; kc++){
    const ushort* asrc = (kc<2) ? xb : (kc<4) ? h1 : (kc<6) ? h2 : h3;
    int koff = (kc&1)*64;
    __syncthreads();
    #pragma unroll
    for(int i=0;i<4;i++){
      int slot = tid + i*256;
      int r = slot>>3, seg = (slot&7)*8;
      int n = nbase + r;
      uint4 v = make_uint4(0,0,0,0);
      if(n < N) v = *(const uint4*)(asrc + (size_t)n*128 + koff + seg);
      *(uint4*)(&Al[r*LDA + seg]) = v;
    }
    #pragma unroll
    for(int i=0;i<4;i++){
      int slot = tid + i*256;
      int r = slot>>3, seg = (slot&7)*8;
      uint4 v = *(const uint4*)(w1t + (size_t)r*512 + kc*64 + seg);
      *(uint4*)(&Bl[r*LDA + seg]) = v;
    }
    __syncthreads();
    #pragma unroll
    for(int ks=0; ks<2; ks++){
      bf16x8 a[4], b[4];
      #pragma unroll
      for(int f=0; f<4; f++){
        a[f] = *(const bf16x8*)&Al[(wr*64 + f*16 + lm)*LDA + ks*32 + kg*8];
        b[f] = *(const bf16x8*)&Bl[(wc*64 + f*16 + lm)*LDA + ks*32 + kg*8];
      }
      #pragma unroll
      for(int fm=0; fm<4; fm++)
        #pragma unroll
        for(int fn=0; fn<4; fn++)
          acc[fm][fn] = __builtin_amdgcn_mfma_f32_16x16x32_bf16(a[fm], b[fn], acc[fm][fn], 0,0,0);
    }
  }
  int crow0 = (lane>>4)*4;
  #pragma unroll
  for(int fm=0; fm<4; fm++){
    #pragma unroll
    for(int fn=0; fn<4; fn++){
      int col = wc*64 + fn*16 + lm;
      float bv = bias[col];
      #pragma unroll
      for(int j=0;j<4;j++){
        int row = nbase + wr*64 + fm*16 + crow0 + j;
        if(row < N){
          float v = fmaxf(acc[fm][fn][j] + bv, 0.f);
          outb[(size_t)row*128 + col] = f2bf(v);
        }
      }
    }
  }
}

// ------- MFMA GEMM layer 2: zstack[N][256] = out1b @ W2t^T (+b2 on cols<40) -------

__global__ void __launch_bounds__(256) k_gemm2(
    const ushort* __restrict__ ab, const ushort* __restrict__ w2t,
    const float* __restrict__ bias, ushort* __restrict__ z, int N){
  __shared__ ushort Al[128*LDA];
  __shared__ ushort Bl[128*LDA];
  int tid = threadIdx.x;
  int wid = tid>>6, lane = tid&63;
  int wr = wid>>1, wc = wid&1;
  int lm = lane&15, kg = lane>>4;
  int nbase = blockIdx.x*128;
  int cb = blockIdx.y;
  f32x4 acc[4][4];
  #pragma unroll
  for(int i=0;i<4;i++)
    #pragma unroll
    for(int j=0;j<4;j++) acc[i][j] = (f32x4){0.f,0.f,0.f,0.f};

  for(int kc=0; kc<2; kc++){
    int koff = kc*64;
    __syncthreads();
    #pragma unroll
    for(int i=0;i<4;i++){
      int slot = tid + i*256;
      int r = slot>>3, seg = (slot&7)*8;
      int n = nbase + r;
      uint4 v = make_uint4(0,0,0,0);
      if(n < N) v = *(const uint4*)(ab + (size_t)n*128 + koff + seg);
      *(uint4*)(&Al[r*LDA + seg]) = v;
    }
    #pragma unroll
    for(int i=0;i<4;i++){
      int slot = tid + i*256;
      int r = slot>>3, seg = (slot&7)*8;
      uint4 v = *(const uint4*)(w2t + (size_t)(cb*128 + r)*128 + koff + seg);
      *(uint4*)(&Bl[r*LDA + seg]) = v;
    }
    __syncthreads();
    #pragma unroll
    for(int ks=0; ks<2; ks++){
      bf16x8 a[4], b[4];
      #pragma unroll
      for(int f=0; f<4; f++){
        a[f] = *(const bf16x8*)&Al[(wr*64 + f*16 + lm)*LDA + ks*32 + kg*8];
        b[f] = *(const bf16x8*)&Bl[(wc*64 + f*16 + lm)*LDA + ks*32 + kg*8];
      }
      #pragma unroll
      for(int fm=0; fm<4; fm++)
        #pragma unroll
        for(int fn=0; fn<4; fn++)
          acc[fm][fn] = __builtin_amdgcn_mfma_f32_16x16x32_bf16(a[fm], b[fn], acc[fm][fn], 0,0,0);
    }
  }
  int crow0 = (lane>>4)*4;
  #pragma unroll
  for(int fm=0; fm<4; fm++){
    #pragma unroll
    for(int fn=0; fn<4; fn++){
      int cc = cb*128 + wc*64 + fn*16 + lm;
      float bv = (cc < 40) ? bias[cc] : 0.f;
      #pragma unroll
      for(int j=0;j<4;j++){
        int row = nbase + wr*64 + fm*16 + crow0 + j;
        if(row < N){
          float v = acc[fm][fn][j] + bv;
          z[(size_t)row*256 + cc] = f2bf(v);
        }
      }
    }
  }
}

// ---------------- host ----------------

extern "C" void kernel_launch(void* const* d_in, const int* in_sizes, int n_in,
                              void* d_out, int out_size, void* d_ws, size_t ws_size,
                              hipStream_t stream){
  const float* x  = (const float*)d_in[0];
  const int*   ei = (const int*)d_in[1];
  const float* w1 = (const float*)d_in[2];
  const float* b1 = (const float*)d_in[3];
  const float* w2 = (const float*)d_in[4];
  const float* b2 = (const float*)d_in[5];
  float* out = (float*)d_out;
  int N = in_sizes[0] / 128;
  int E = in_sizes[1] / 2;
  const int* rowv = ei;
  const int* colv = ei + E;
  int NB = (N + 255) >> 8;

  char* wsp = (char*)d_ws;
  size_t off = 0;
  auto alloc = [&](size_t bytes)->void*{
    void* p = wsp + off;
    off = (off + bytes + 255) & ~(size_t)255;
    return p;
  };
  float*    dis    = (float*)   alloc((size_t)N*4);
  int*      rowptr = (int*)     alloc((size_t)(N+1)*4);
  int*      hcnt   = (int*)     alloc(512*4);
  int*      bbase  = (int*)     alloc(513*4);
  int*      gcur   = (int*)     alloc(512*4);
  unsigned* part   = (unsigned*)alloc((size_t)E*4);
  unsigned* ed4    = (unsigned*)alloc((size_t)E*4);
  uint2*    ed8    = (uint2*)   alloc((size_t)E*8);
  ushort*   xb     = (ushort*)  alloc((size_t)N*128*2);
  ushort*   hb1    = (ushort*)  alloc((size_t)N*128*2);
  ushort*   hb2    = (ushort*)  alloc((size_t)N*128*2);
  ushort*   hb3    = (ushort*)  alloc((size_t)N*128*2);
  ushort*   out1b  = (ushort*)  alloc((size_t)N*128*2);
  ushort*   w1t    = (ushort*)  alloc(128*512*2);
  ushort*   w2t    = (ushort*)  alloc(256*128*2);
  ushort*   zst    = (ushort*)  alloc((size_t)N*256*2);
  ushort*   ta     = hb1;   // dead after k_gemm1
  ushort*   tb     = hb2;
  (void)ws_size;

  int pb = (E+PT-1)/PT;
  int sg = (N+3)/4;
  int gb = (N+127)/128;

  hipMemsetAsync(hcnt, 0, 512*4, stream);
  k_phist <<<pb, 256, 0, stream>>>(colv, hcnt, E);
  k_bscan <<<1, 512, 0, stream>>>(hcnt, bbase, gcur, rowptr, NB, N);
  k_part  <<<pb, 256, 0, stream>>>(rowv, colv, gcur, part, E);
  k_csort <<<NB, 256, 0, stream>>>(part, bbase, dis, ed4, rowptr, N);
  k_wfill <<<sg, 256, 0, stream>>>(ed4, rowptr, dis, ed8, N);

  k_cast_x <<<(N*32+255)/256, 256, 0, stream>>>(x, xb, N*32);
  k_castw1 <<<256, 256, 0, stream>>>(w1, w1t);
  k_castw2 <<<128, 256, 0, stream>>>(w2, w2t);

  // layer 1: propagate width-128 bf16
  k_spmm1<<<sg, 256, 0, stream>>>(xb,  hb1, rowptr, ed8, N);
  k_spmm1<<<sg, 256, 0, stream>>>(hb1, hb2, rowptr, ed8, N);
  k_spmm1<<<sg, 256, 0, stream>>>(hb2, hb3, rowptr, ed8, N);
  k_gemm1<<<gb, 256, 0, stream>>>(xb, hb1, hb2, hb3, w1t, b1, out1b, N);
  // layer 2: z_k = H @ W2_k, then Horner propagation at width 64
  k_gemm2<<<dim3(gb,2), 256, 0, stream>>>(out1b, w2t, b2, zst, N);
  k_spmm2    <<<sg, 256, 0, stream>>>(zst+192, 256, zst+128, 256, ta, rowptr, ed8, N);
  k_spmm2    <<<sg, 256, 0, stream>>>(ta,       64, zst+64,  256, tb, rowptr, ed8, N);
  k_spmm2_lsm<<<sg, 256, 0, stream>>>(tb,       64, zst,     256, out, rowptr, ed8, N);
}

// Round 10
// 509.389 us; speedup vs baseline: 1.2937x; 1.0124x over previous
//
#include <hip/hip_runtime.h>
#include <math.h>

typedef __bf16 bf16x8 __attribute__((ext_vector_type(8)));
typedef float  f32x4  __attribute__((ext_vector_type(4)));
typedef unsigned u32x4 __attribute__((ext_vector_type(4)));

__device__ __forceinline__ unsigned short f2bf(float f){
  unsigned u = __float_as_uint(f);
  unsigned r = (u + 0x7fffu + ((u>>16)&1u)) >> 16;
  return (unsigned short)r;
}
__device__ __forceinline__ float bflo(unsigned v){ return __uint_as_float(v<<16); }
__device__ __forceinline__ float bfhi(unsigned v){ return __uint_as_float(v & 0xffff0000u); }

// ---------------- bucket histogram (256-node buckets) ----------------

#define PT 4096

__global__ void __launch_bounds__(256) k_phist(const int* __restrict__ colv,
                                               int* __restrict__ hcnt, int E){
  __shared__ int lh[512];
  int tid = threadIdx.x;
  for(int i=tid;i<512;i+=256) lh[i]=0;
  __syncthreads();
  int base = blockIdx.x*PT;
  int bmax = E - base; if(bmax > PT) bmax = PT;
  for(int k=tid;k<bmax;k+=256){
    int c = colv[base+k];
    atomicAdd(&lh[c>>8],1);
  }
  __syncthreads();
  for(int i=tid;i<512;i+=256){
    int cnt = lh[i];
    if(cnt>0) atomicAdd(&hcnt[i],cnt);
  }
}

// single block: scan hcnt -> bbase[513], init gcur, rowptr[N]=E
__global__ void __launch_bounds__(512) k_bscan(const int* __restrict__ hcnt,
                                               int* __restrict__ bbase, int* __restrict__ gcur,
                                               int* __restrict__ rowptr, int NB, int N){
  __shared__ int ts[512];
  int tid = threadIdx.x;
  int v = (tid<NB) ? hcnt[tid] : 0;
  ts[tid]=v; __syncthreads();
  for(int o=1;o<512;o<<=1){
    int t=(tid>=o)?ts[tid-o]:0; __syncthreads();
    ts[tid]+=t; __syncthreads();
  }
  int ex = ts[tid]-v;
  if(tid<=NB) bbase[tid] = (tid<NB) ? ex : ts[NB-1];
  if(tid<NB)  gcur[tid]  = ex;
  if(tid==0)  rowptr[N]  = ts[511];
}

// ---------------- partition into buckets: part[pos] = (colLow8<<24) | src ----------------

__global__ void __launch_bounds__(256) k_part(const int* __restrict__ rowv,
                                              const int* __restrict__ colv,
                                              int* __restrict__ gcur,
                                              unsigned* __restrict__ part, int E){
  __shared__ int lh[512];
  __shared__ int lb[512];
  int tid = threadIdx.x;
  for(int i=tid;i<512;i+=256) lh[i]=0;
  __syncthreads();
  int base = blockIdx.x*PT;
  int bmax = E - base; if(bmax > PT) bmax = PT;
  for(int k=tid;k<bmax;k+=256){
    int c = colv[base+k];
    atomicAdd(&lh[c>>8],1);
  }
  __syncthreads();
  for(int i=tid;i<512;i+=256){
    int cnt = lh[i];
    lb[i] = cnt>0 ? atomicAdd(&gcur[i],cnt) : 0;
  }
  __syncthreads();
  for(int i=tid;i<512;i+=256) lh[i]=0;
  __syncthreads();
  for(int k=tid;k<bmax;k+=256){
    int r = rowv[base+k], c = colv[base+k];
    int b = c>>8;
    int pos = lb[b] + atomicAdd(&lh[b],1);
    part[pos] = ((unsigned)(c&255)<<24) | (unsigned)r;
  }
}

// ------- per-bucket counting sort -> ed4 (src), rowptr, dis -------

#define CAP 6144

__global__ void __launch_bounds__(256) k_csort(const unsigned* __restrict__ part,
                                               const int* __restrict__ bbase,
                                               float* __restrict__ dis,
                                               unsigned* __restrict__ ed4,
                                               int* __restrict__ rowptr, int N){
  __shared__ unsigned st[CAP];
  __shared__ int cnt[256];
  __shared__ int ts[256];
  int b = blockIdx.x, tid = threadIdx.x;
  int nb0 = b<<8;
  int g0 = bbase[b], g1 = bbase[b+1];
  int ce = g1-g0;
  cnt[tid]=0; __syncthreads();
  for(int i=tid;i<ce;i+=256){
    atomicAdd(&cnt[part[g0+i]>>24],1);
  }
  __syncthreads();
  int v = cnt[tid];
  ts[tid]=v; __syncthreads();
  for(int o=1;o<256;o<<=1){
    int t=(tid>=o)?ts[tid-o]:0; __syncthreads();
    ts[tid]+=t; __syncthreads();
  }
  int ex = ts[tid]-v;
  int node = nb0+tid;
  if(node < N){
    rowptr[node] = g0 + ex;
    dis[node] = v > 0 ? rsqrtf((float)v) : 0.f;
  }
  cnt[tid] = ex;
  __syncthreads();
  for(int i=tid;i<ce;i+=256){
    unsigned pc = part[g0+i];
    int pos = atomicAdd(&cnt[pc>>24],1);
    if(pos < CAP) st[pos] = pc & 0xFFFFFFu;
  }
  __syncthreads();
  for(int i=tid;i<ce;i+=256) ed4[g0+i] = st[i];
}

// ------- weight fill: ed8[e] = {src, dis[src]*dis[n]}, coalesced -------

__global__ void __launch_bounds__(256) k_wfill(const unsigned* __restrict__ ed4,
                                               const int* __restrict__ rowptr,
                                               const float* __restrict__ dis,
                                               uint2* __restrict__ ed8, int N){
  int wid = threadIdx.x>>6, lane = threadIdx.x&63;
  int n = blockIdx.x*4 + wid;
  if(n>=N) return;
  int s = rowptr[n], e = rowptr[n+1];
  float dc = dis[n];
  for(int i=s+lane; i<e; i+=64){
    unsigned r = ed4[i];
    ed8[i] = make_uint2(r, __float_as_uint(dis[r]*dc));
  }
}

// ---------------- casts ----------------

__global__ void k_cast_x(const float* __restrict__ x, ushort* __restrict__ xb, int n4){
  int t = blockIdx.x*256 + threadIdx.x;
  if(t < n4){
    float4 v = ((const float4*)x)[t];
    uint2 o;
    o.x = (unsigned)f2bf(v.x) | ((unsigned)f2bf(v.y)<<16);
    o.y = (unsigned)f2bf(v.z) | ((unsigned)f2bf(v.w)<<16);
    ((uint2*)xb)[t] = o;
  }
}

__global__ void k_castw1(const float* __restrict__ w1, ushort* __restrict__ w1t){
  int i = blockIdx.x*256 + threadIdx.x;   // 65536
  int n = i & 127, kin = (i>>7)&127, s = i>>14;
  w1t[n*512 + s*128 + kin] = f2bf(w1[i]);
}

__global__ void k_castw2(const float* __restrict__ w2, ushort* __restrict__ w2t){
  int i = blockIdx.x*256 + threadIdx.x;   // 32768
  int k = i & 127, np = i>>7;
  int s = np>>6, nn = np&63;
  float v = (nn<40) ? w2[(s*128 + k)*40 + nn] : 0.f;
  w2t[i] = f2bf(v);
}

// ------- SpMM width-128: 4 groups x 4 edges in flight per iter -------

#define FMA8(vv, ww) \
  a[0]+=ww*bflo(vv.x); a[1]+=ww*bfhi(vv.x); \
  a[2]+=ww*bflo(vv.y); a[3]+=ww*bfhi(vv.y); \
  a[4]+=ww*bflo(vv.z); a[5]+=ww*bfhi(vv.z); \
  a[6]+=ww*bflo(vv.w); a[7]+=ww*bfhi(vv.w);

__global__ void __launch_bounds__(256) k_spmm1(
    const ushort* __restrict__ src, ushort* __restrict__ dst,
    const int* __restrict__ rowptr, const uint2* __restrict__ ed, int N){
  int wid = threadIdx.x>>6, lane = threadIdx.x&63;
  int n = blockIdx.x*4 + wid;
  if(n>=N) return;
  int p = lane>>4, c = lane&15;
  int s = rowptr[n], e = rowptr[n+1];
  float a[8];
  #pragma unroll
  for(int i=0;i<8;i++) a[i]=0.f;
  for(int b=s; b<e; b+=64){
    int m = e-b; if(m>64) m=64;
    uint2 eD = make_uint2(0u,0u);
    if(lane<m) eD = ed[b+lane];
    int tmax = (m+15)>>4;
    for(int t=0;t<tmax;t++){
      int j = 16*t + 4*p;
      int r0 = __shfl((int)eD.x, j);
      int r1 = __shfl((int)eD.x, j+1);
      int r2 = __shfl((int)eD.x, j+2);
      int r3 = __shfl((int)eD.x, j+3);
      float w0 = __uint_as_float(__shfl((int)eD.y, j));
      float w1 = __uint_as_float(__shfl((int)eD.y, j+1));
      float w2 = __uint_as_float(__shfl((int)eD.y, j+2));
      float w3 = __uint_as_float(__shfl((int)eD.y, j+3));
      uint4 v0 = *(const uint4*)(src + (size_t)r0*128 + c*8);
      uint4 v1 = *(const uint4*)(src + (size_t)r1*128 + c*8);
      uint4 v2 = *(const uint4*)(src + (size_t)r2*128 + c*8);
      uint4 v3 = *(const uint4*)(src + (size_t)r3*128 + c*8);
      FMA8(v0, w0)
      FMA8(v1, w1)
      FMA8(v2, w2)
      FMA8(v3, w3)
    }
  }
  #pragma unroll
  for(int i=0;i<8;i++){ a[i]+=__shfl_xor(a[i],32); a[i]+=__shfl_xor(a[i],16); }
  if(p==0){
    u32x4 o;
    o.x = (unsigned)f2bf(a[0]) | ((unsigned)f2bf(a[1])<<16);
    o.y = (unsigned)f2bf(a[2]) | ((unsigned)f2bf(a[3])<<16);
    o.z = (unsigned)f2bf(a[4]) | ((unsigned)f2bf(a[5])<<16);
    o.w = (unsigned)f2bf(a[6]) | ((unsigned)f2bf(a[7])<<16);
    __builtin_nontemporal_store(o, (u32x4*)(dst + (size_t)n*128 + c*8));
  }
}

// ------- SpMM width-64 + add z: 8 groups x 4 edges in flight -------

__global__ void __launch_bounds__(256) k_spmm2(
    const ushort* __restrict__ tprev, int ss,
    const ushort* __restrict__ z, int zs,
    ushort* __restrict__ tnew,
    const int* __restrict__ rowptr, const uint2* __restrict__ ed, int N){
  int wid = threadIdx.x>>6, lane = threadIdx.x&63;
  int n = blockIdx.x*4 + wid;
  if(n>=N) return;
  int p = lane>>3, c = lane&7;
  int s = rowptr[n], e = rowptr[n+1];
  float a[8];
  #pragma unroll
  for(int i=0;i<8;i++) a[i]=0.f;
  for(int b=s; b<e; b+=64){
    int m = e-b; if(m>64) m=64;
    uint2 eD = make_uint2(0u,0u);
    if(lane<m) eD = ed[b+lane];
    int tmax = (m+31)>>5;
    for(int t=0;t<tmax;t++){
      int j = 32*t + 4*p;
      int r0 = __shfl((int)eD.x, j);
      int r1 = __shfl((int)eD.x, j+1);
      int r2 = __shfl((int)eD.x, j+2);
      int r3 = __shfl((int)eD.x, j+3);
      float w0 = __uint_as_float(__shfl((int)eD.y, j));
      float w1 = __uint_as_float(__shfl((int)eD.y, j+1));
      float w2 = __uint_as_float(__shfl((int)eD.y, j+2));
      float w3 = __uint_as_float(__shfl((int)eD.y, j+3));
      uint4 v0 = *(const uint4*)(tprev + (size_t)r0*ss + c*8);
      uint4 v1 = *(const uint4*)(tprev + (size_t)r1*ss + c*8);
      uint4 v2 = *(const uint4*)(tprev + (size_t)r2*ss + c*8);
      uint4 v3 = *(const uint4*)(tprev + (size_t)r3*ss + c*8);
      FMA8(v0, w0)
      FMA8(v1, w1)
      FMA8(v2, w2)
      FMA8(v3, w3)
    }
  }
  #pragma unroll
  for(int i=0;i<8;i++){ a[i]+=__shfl_xor(a[i],32); a[i]+=__shfl_xor(a[i],16); a[i]+=__shfl_xor(a[i],8); }
  if(lane<8){
    uint4 vz = *(const uint4*)(z + (size_t)n*zs + c*8);
    a[0]+=bflo(vz.x); a[1]+=bfhi(vz.x);
    a[2]+=bflo(vz.y); a[3]+=bfhi(vz.y);
    a[4]+=bflo(vz.z); a[5]+=bfhi(vz.z);
    a[6]+=bflo(vz.w); a[7]+=bfhi(vz.w);
    u32x4 o;
    o.x = (unsigned)f2bf(a[0]) | ((unsigned)f2bf(a[1])<<16);
    o.y = (unsigned)f2bf(a[2]) | ((unsigned)f2bf(a[3])<<16);
    o.z = (unsigned)f2bf(a[4]) | ((unsigned)f2bf(a[5])<<16);
    o.w = (unsigned)f2bf(a[6]) | ((unsigned)f2bf(a[7])<<16);
    __builtin_nontemporal_store(o, (u32x4*)(tnew + (size_t)n*64 + c*8));
  }
}

// Final: out = log_softmax(A*tprev + z0) cols 0..39, f32 [N][40]

__global__ void __launch_bounds__(256) k_spmm2_lsm(
    const ushort* __restrict__ tprev, int ss,
    const ushort* __restrict__ z, int zs,
    float* __restrict__ out,
    const int* __restrict__ rowptr, const uint2* __restrict__ ed, int N){
  int wid = threadIdx.x>>6, lane = threadIdx.x&63;
  int n = blockIdx.x*4 + wid;
  if(n>=N) return;
  int p = lane>>3, c = lane&7;
  int s = rowptr[n], e = rowptr[n+1];
  float a[8];
  #pragma unroll
  for(int i=0;i<8;i++) a[i]=0.f;
  for(int b=s; b<e; b+=64){
    int m = e-b; if(m>64) m=64;
    uint2 eD = make_uint2(0u,0u);
    if(lane<m) eD = ed[b+lane];
    int tmax = (m+31)>>5;
    for(int t=0;t<tmax;t++){
      int j = 32*t + 4*p;
      int r0 = __shfl((int)eD.x, j);
      int r1 = __shfl((int)eD.x, j+1);
      int r2 = __shfl((int)eD.x, j+2);
      int r3 = __shfl((int)eD.x, j+3);
      float w0 = __uint_as_float(__shfl((int)eD.y, j));
      float w1 = __uint_as_float(__shfl((int)eD.y, j+1));
      float w2 = __uint_as_float(__shfl((int)eD.y, j+2));
      float w3 = __uint_as_float(__shfl((int)eD.y, j+3));
      uint4 v0 = *(const uint4*)(tprev + (size_t)r0*ss + c*8);
      uint4 v1 = *(const uint4*)(tprev + (size_t)r1*ss + c*8);
      uint4 v2 = *(const uint4*)(tprev + (size_t)r2*ss + c*8);
      uint4 v3 = *(const uint4*)(tprev + (size_t)r3*ss + c*8);
      FMA8(v0, w0)
      FMA8(v1, w1)
      FMA8(v2, w2)
      FMA8(v3, w3)
    }
  }
  #pragma unroll
  for(int i=0;i<8;i++){ a[i]+=__shfl_xor(a[i],32); a[i]+=__shfl_xor(a[i],16); a[i]+=__shfl_xor(a[i],8); }
  uint4 vz = *(const uint4*)(z + (size_t)n*zs + c*8);
  a[0]+=bflo(vz.x); a[1]+=bfhi(vz.x);
  a[2]+=bflo(vz.y); a[3]+=bfhi(vz.y);
  a[4]+=bflo(vz.z); a[5]+=bfhi(vz.z);
  a[6]+=bflo(vz.w); a[7]+=bfhi(vz.w);
  bool valid = (c < 5);
  float mx = -1e30f;
  #pragma unroll
  for(int i=0;i<8;i++) if(valid) mx = fmaxf(mx, a[i]);
  #pragma unroll
  for(int o=1;o<8;o<<=1) mx = fmaxf(mx, __shfl_xor(mx, o));
  float sum = 0.f;
  #pragma unroll
  for(int i=0;i<8;i++) if(valid) sum += expf(a[i]-mx);
  #pragma unroll
  for(int o=1;o<8;o<<=1) sum += __shfl_xor(sum, o);
  float l = mx + logf(sum);
  if(lane<8 && valid){
    f32x4 o0, o1;
    o0[0]=a[0]-l; o0[1]=a[1]-l; o0[2]=a[2]-l; o0[3]=a[3]-l;
    o1[0]=a[4]-l; o1[1]=a[5]-l; o1[2]=a[6]-l; o1[3]=a[7]-l;
    float* op = out + (size_t)n*40 + c*8;
    __builtin_nontemporal_store(o0, (f32x4*)op);
    __builtin_nontemporal_store(o1, (f32x4*)(op+4));
  }
}

// ---------------- MFMA GEMM layer 1 ----------------

#define LDA 72

__global__ void __launch_bounds__(256) k_gemm1(
    const ushort* __restrict__ xb, const ushort* __restrict__ h1,
    const ushort* __restrict__ h2, const ushort* __restrict__ h3,
    const ushort* __restrict__ w1t, const float* __restrict__ bias,
    ushort* __restrict__ outb, int N){
  __shared__ ushort Al[128*LDA];
  __shared__ ushort Bl[128*LDA];
  int tid = threadIdx.x;
  int wid = tid>>6, lane = tid&63;
  int wr = wid>>1, wc = wid&1;
  int lm = lane&15, kg = lane>>4;
  int nbase = blockIdx.x*128;
  f32x4 acc[4][4];
  #pragma unroll
  for(int i=0;i<4;i++)
    #pragma unroll
    for(int j=0;j<4;j++) acc[i][j] = (f32x4){0.f,0.f,0.f,0.f};

  for(int kc=0; kc<8; kc++){
    const ushort* asrc = (kc<2) ? xb : (kc<4) ? h1 : (kc<6) ? h2 : h3;
    int koff = (kc&1)*64;
    __syncthreads();
    #pragma unroll
    for(int i=0;i<4;i++){
      int slot = tid + i*256;
      int r = slot>>3, seg = (slot&7)*8;
      int n = nbase + r;
      uint4 v = make_uint4(0,0,0,0);
      if(n < N) v = *(const uint4*)(asrc + (size_t)n*128 + koff + seg);
      *(uint4*)(&Al[r*LDA + seg]) = v;
    }
    #pragma unroll
    for(int i=0;i<4;i++){
      int slot = tid + i*256;
      int r = slot>>3, seg = (slot&7)*8;
      uint4 v = *(const uint4*)(w1t + (size_t)r*512 + kc*64 + seg);
      *(uint4*)(&Bl[r*LDA + seg]) = v;
    }
    __syncthreads();
    #pragma unroll
    for(int ks=0; ks<2; ks++){
      bf16x8 a[4], b[4];
      #pragma unroll
      for(int f=0; f<4; f++){
        a[f] = *(const bf16x8*)&Al[(wr*64 + f*16 + lm)*LDA + ks*32 + kg*8];
        b[f] = *(const bf16x8*)&Bl[(wc*64 + f*16 + lm)*LDA + ks*32 + kg*8];
      }
      #pragma unroll
      for(int fm=0; fm<4; fm++)
        #pragma unroll
        for(int fn=0; fn<4; fn++)
          acc[fm][fn] = __builtin_amdgcn_mfma_f32_16x16x32_bf16(a[fm], b[fn], acc[fm][fn], 0,0,0);
    }
  }
  int crow0 = (lane>>4)*4;
  #pragma unroll
  for(int fm=0; fm<4; fm++){
    #pragma unroll
    for(int fn=0; fn<4; fn++){
      int col = wc*64 + fn*16 + lm;
      float bv = bias[col];
      #pragma unroll
      for(int j=0;j<4;j++){
        int row = nbase + wr*64 + fm*16 + crow0 + j;
        if(row < N){
          float v = fmaxf(acc[fm][fn][j] + bv, 0.f);
          outb[(size_t)row*128 + col] = f2bf(v);
        }
      }
    }
  }
}

// ------- MFMA GEMM layer 2: zstack[N][256] = out1b @ W2t^T (+b2 on cols<40) -------

__global__ void __launch_bounds__(256) k_gemm2(
    const ushort* __restrict__ ab, const ushort* __restrict__ w2t,
    const float* __restrict__ bias, ushort* __restrict__ z, int N){
  __shared__ ushort Al[128*LDA];
  __shared__ ushort Bl[128*LDA];
  int tid = threadIdx.x;
  int wid = tid>>6, lane = tid&63;
  int wr = wid>>1, wc = wid&1;
  int lm = lane&15, kg = lane>>4;
  int nbase = blockIdx.x*128;
  int cb = blockIdx.y;
  f32x4 acc[4][4];
  #pragma unroll
  for(int i=0;i<4;i++)
    #pragma unroll
    for(int j=0;j<4;j++) acc[i][j] = (f32x4){0.f,0.f,0.f,0.f};

  for(int kc=0; kc<2; kc++){
    int koff = kc*64;
    __syncthreads();
    #pragma unroll
    for(int i=0;i<4;i++){
      int slot = tid + i*256;
      int r = slot>>3, seg = (slot&7)*8;
      int n = nbase + r;
      uint4 v = make_uint4(0,0,0,0);
      if(n < N) v = *(const uint4*)(ab + (size_t)n*128 + koff + seg);
      *(uint4*)(&Al[r*LDA + seg]) = v;
    }
    #pragma unroll
    for(int i=0;i<4;i++){
      int slot = tid + i*256;
      int r = slot>>3, seg = (slot&7)*8;
      uint4 v = *(const uint4*)(w2t + (size_t)(cb*128 + r)*128 + koff + seg);
      *(uint4*)(&Bl[r*LDA + seg]) = v;
    }
    __syncthreads();
    #pragma unroll
    for(int ks=0; ks<2; ks++){
      bf16x8 a[4], b[4];
      #pragma unroll
      for(int f=0; f<4; f++){
        a[f] = *(const bf16x8*)&Al[(wr*64 + f*16 + lm)*LDA + ks*32 + kg*8];
        b[f] = *(const bf16x8*)&Bl[(wc*64 + f*16 + lm)*LDA + ks*32 + kg*8];
      }
      #pragma unroll
      for(int fm=0; fm<4; fm++)
        #pragma unroll
        for(int fn=0; fn<4; fn++)
          acc[fm][fn] = __builtin_amdgcn_mfma_f32_16x16x32_bf16(a[fm], b[fn], acc[fm][fn], 0,0,0);
    }
  }
  int crow0 = (lane>>4)*4;
  #pragma unroll
  for(int fm=0; fm<4; fm++){
    #pragma unroll
    for(int fn=0; fn<4; fn++){
      int cc = cb*128 + wc*64 + fn*16 + lm;
      float bv = (cc < 40) ? bias[cc] : 0.f;
      #pragma unroll
      for(int j=0;j<4;j++){
        int row = nbase + wr*64 + fm*16 + crow0 + j;
        if(row < N){
          float v = acc[fm][fn][j] + bv;
          z[(size_t)row*256 + cc] = f2bf(v);
        }
      }
    }
  }
}

// ---------------- host ----------------

extern "C" void kernel_launch(void* const* d_in, const int* in_sizes, int n_in,
                              void* d_out, int out_size, void* d_ws, size_t ws_size,
                              hipStream_t stream){
  const float* x  = (const float*)d_in[0];
  const int*   ei = (const int*)d_in[1];
  const float* w1 = (const float*)d_in[2];
  const float* b1 = (const float*)d_in[3];
  const float* w2 = (const float*)d_in[4];
  const float* b2 = (const float*)d_in[5];
  float* out = (float*)d_out;
  int N = in_sizes[0] / 128;
  int E = in_sizes[1] / 2;
  const int* rowv = ei;
  const int* colv = ei + E;
  int NB = (N + 255) >> 8;

  char* wsp = (char*)d_ws;
  size_t off = 0;
  auto alloc = [&](size_t bytes)->void*{
    void* p = wsp + off;
    off = (off + bytes + 255) & ~(size_t)255;
    return p;
  };
  float*    dis    = (float*)   alloc((size_t)N*4);
  int*      rowptr = (int*)     alloc((size_t)(N+1)*4);
  int*      hcnt   = (int*)     alloc(512*4);
  int*      bbase  = (int*)     alloc(513*4);
  int*      gcur   = (int*)     alloc(512*4);
  unsigned* part   = (unsigned*)alloc((size_t)E*4);
  unsigned* ed4    = (unsigned*)alloc((size_t)E*4);
  uint2*    ed8    = (uint2*)   alloc((size_t)E*8);
  ushort*   xb     = (ushort*)  alloc((size_t)N*128*2);
  ushort*   hb1    = (ushort*)  alloc((size_t)N*128*2);
  ushort*   hb2    = (ushort*)  alloc((size_t)N*128*2);
  ushort*   hb3    = (ushort*)  alloc((size_t)N*128*2);
  ushort*   out1b  = (ushort*)  alloc((size_t)N*128*2);
  ushort*   w1t    = (ushort*)  alloc(128*512*2);
  ushort*   w2t    = (ushort*)  alloc(256*128*2);
  ushort*   zst    = (ushort*)  alloc((size_t)N*256*2);
  ushort*   ta     = hb1;   // dead after k_gemm1
  ushort*   tb     = hb2;
  (void)ws_size;

  int pb = (E+PT-1)/PT;
  int sg = (N+3)/4;
  int gb = (N+127)/128;

  hipMemsetAsync(hcnt, 0, 512*4, stream);
  k_phist <<<pb, 256, 0, stream>>>(colv, hcnt, E);
  k_bscan <<<1, 512, 0, stream>>>(hcnt, bbase, gcur, rowptr, NB, N);
  k_part  <<<pb, 256, 0, stream>>>(rowv, colv, gcur, part, E);
  k_csort <<<NB, 256, 0, stream>>>(part, bbase, dis, ed4, rowptr, N);
  k_wfill <<<sg, 256, 0, stream>>>(ed4, rowptr, dis, ed8, N);

  k_cast_x <<<(N*32+255)/256, 256, 0, stream>>>(x, xb, N*32);
  k_castw1 <<<256, 256, 0, stream>>>(w1, w1t);
  k_castw2 <<<128, 256, 0, stream>>>(w2, w2t);

  // layer 1: propagate width-128 bf16
  k_spmm1<<<sg, 256, 0, stream>>>(xb,  hb1, rowptr, ed8, N);
  k_spmm1<<<sg, 256, 0, stream>>>(hb1, hb2, rowptr, ed8, N);
  k_spmm1<<<sg, 256, 0, stream>>>(hb2, hb3, rowptr, ed8, N);
  k_gemm1<<<gb, 256, 0, stream>>>(xb, hb1, hb2, hb3, w1t, b1, out1b, N);
  // layer 2: z_k = H @ W2_k, then Horner propagation at width 64
  k_gemm2<<<dim3(gb,2), 256, 0, stream>>>(out1b, w2t, b2, zst, N);
  k_spmm2    <<<sg, 256, 0, stream>>>(zst+192, 256, zst+128, 256, ta, rowptr, ed8, N);
  k_spmm2    <<<sg, 256, 0, stream>>>(ta,       64, zst+64,  256, tb, rowptr, ed8, N);
  k_spmm2_lsm<<<sg, 256, 0, stream>>>(tb,       64, zst,     256, out, rowptr, ed8, N);
}

// Round 11
// 467.850 us; speedup vs baseline: 1.4085x; 1.0888x over previous
//
#include <hip/hip_runtime.h>
#include <math.h>

typedef __bf16 bf16x8 __attribute__((ext_vector_type(8)));
typedef float  f32x4  __attribute__((ext_vector_type(4)));
typedef unsigned u32x4 __attribute__((ext_vector_type(4)));

__device__ __forceinline__ unsigned short f2bf(float f){
  unsigned u = __float_as_uint(f);
  unsigned r = (u + 0x7fffu + ((u>>16)&1u)) >> 16;
  return (unsigned short)r;
}
__device__ __forceinline__ float bflo(unsigned v){ return __uint_as_float(v<<16); }
__device__ __forceinline__ float bfhi(unsigned v){ return __uint_as_float(v & 0xffff0000u); }

// ---------------- bucket histogram (256-node buckets) ----------------

#define PT 4096

__global__ void __launch_bounds__(256) k_phist(const int* __restrict__ colv,
                                               int* __restrict__ hcnt, int E){
  __shared__ int lh[512];
  int tid = threadIdx.x;
  for(int i=tid;i<512;i+=256) lh[i]=0;
  __syncthreads();
  int base = blockIdx.x*PT;
  int bmax = E - base; if(bmax > PT) bmax = PT;
  for(int k=tid;k<bmax;k+=256){
    int c = colv[base+k];
    atomicAdd(&lh[c>>8],1);
  }
  __syncthreads();
  for(int i=tid;i<512;i+=256){
    int cnt = lh[i];
    if(cnt>0) atomicAdd(&hcnt[i],cnt);
  }
}

// single block: scan hcnt -> bbase[513], init gcur, rowptr[N]=E
__global__ void __launch_bounds__(512) k_bscan(const int* __restrict__ hcnt,
                                               int* __restrict__ bbase, int* __restrict__ gcur,
                                               int* __restrict__ rowptr, int NB, int N){
  __shared__ int ts[512];
  int tid = threadIdx.x;
  int v = (tid<NB) ? hcnt[tid] : 0;
  ts[tid]=v; __syncthreads();
  for(int o=1;o<512;o<<=1){
    int t=(tid>=o)?ts[tid-o]:0; __syncthreads();
    ts[tid]+=t; __syncthreads();
  }
  int ex = ts[tid]-v;
  if(tid<=NB) bbase[tid] = (tid<NB) ? ex : ts[NB-1];
  if(tid<NB)  gcur[tid]  = ex;
  if(tid==0)  rowptr[N]  = ts[511];
}

// ---------------- partition into buckets: part[pos] = (colLow8<<24) | src ----------------

__global__ void __launch_bounds__(256) k_part(const int* __restrict__ rowv,
                                              const int* __restrict__ colv,
                                              int* __restrict__ gcur,
                                              unsigned* __restrict__ part, int E){
  __shared__ int lh[512];
  __shared__ int lb[512];
  int tid = threadIdx.x;
  for(int i=tid;i<512;i+=256) lh[i]=0;
  __syncthreads();
  int base = blockIdx.x*PT;
  int bmax = E - base; if(bmax > PT) bmax = PT;
  for(int k=tid;k<bmax;k+=256){
    int c = colv[base+k];
    atomicAdd(&lh[c>>8],1);
  }
  __syncthreads();
  for(int i=tid;i<512;i+=256){
    int cnt = lh[i];
    lb[i] = cnt>0 ? atomicAdd(&gcur[i],cnt) : 0;
  }
  __syncthreads();
  for(int i=tid;i<512;i+=256) lh[i]=0;
  __syncthreads();
  for(int k=tid;k<bmax;k+=256){
    int r = rowv[base+k], c = colv[base+k];
    int b = c>>8;
    int pos = lb[b] + atomicAdd(&lh[b],1);
    part[pos] = ((unsigned)(c&255)<<24) | (unsigned)r;
  }
}

// ------- per-bucket counting sort -> ed4 (src), rowptr, dis -------

#define CAP 6144

__global__ void __launch_bounds__(256) k_csort(const unsigned* __restrict__ part,
                                               const int* __restrict__ bbase,
                                               float* __restrict__ dis,
                                               unsigned* __restrict__ ed4,
                                               int* __restrict__ rowptr, int N){
  __shared__ unsigned st[CAP];
  __shared__ int cnt[256];
  __shared__ int ts[256];
  int b = blockIdx.x, tid = threadIdx.x;
  int nb0 = b<<8;
  int g0 = bbase[b], g1 = bbase[b+1];
  int ce = g1-g0;
  cnt[tid]=0; __syncthreads();
  for(int i=tid;i<ce;i+=256){
    atomicAdd(&cnt[part[g0+i]>>24],1);
  }
  __syncthreads();
  int v = cnt[tid];
  ts[tid]=v; __syncthreads();
  for(int o=1;o<256;o<<=1){
    int t=(tid>=o)?ts[tid-o]:0; __syncthreads();
    ts[tid]+=t; __syncthreads();
  }
  int ex = ts[tid]-v;
  int node = nb0+tid;
  if(node < N){
    rowptr[node] = g0 + ex;
    dis[node] = v > 0 ? rsqrtf((float)v) : 0.f;
  }
  cnt[tid] = ex;
  __syncthreads();
  for(int i=tid;i<ce;i+=256){
    unsigned pc = part[g0+i];
    int pos = atomicAdd(&cnt[pc>>24],1);
    if(pos < CAP) st[pos] = pc & 0xFFFFFFu;
  }
  __syncthreads();
  for(int i=tid;i<ce;i+=256) ed4[g0+i] = st[i];
}

// ------- weight fill: ed8[e] = {src, dis[src]*dis[n]}, coalesced -------

__global__ void __launch_bounds__(256) k_wfill(const unsigned* __restrict__ ed4,
                                               const int* __restrict__ rowptr,
                                               const float* __restrict__ dis,
                                               uint2* __restrict__ ed8, int N){
  int wid = threadIdx.x>>6, lane = threadIdx.x&63;
  int n = blockIdx.x*4 + wid;
  if(n>=N) return;
  int s = rowptr[n], e = rowptr[n+1];
  float dc = dis[n];
  for(int i=s+lane; i<e; i+=64){
    unsigned r = ed4[i];
    ed8[i] = make_uint2(r, __float_as_uint(dis[r]*dc));
  }
}

// ---------------- casts ----------------

__global__ void k_cast_x(const float* __restrict__ x, ushort* __restrict__ xb, int n4){
  int t = blockIdx.x*256 + threadIdx.x;
  if(t < n4){
    float4 v = ((const float4*)x)[t];
    uint2 o;
    o.x = (unsigned)f2bf(v.x) | ((unsigned)f2bf(v.y)<<16);
    o.y = (unsigned)f2bf(v.z) | ((unsigned)f2bf(v.w)<<16);
    ((uint2*)xb)[t] = o;
  }
}

__global__ void k_castw1(const float* __restrict__ w1, ushort* __restrict__ w1t){
  int i = blockIdx.x*256 + threadIdx.x;   // 65536
  int n = i & 127, kin = (i>>7)&127, s = i>>14;
  w1t[n*512 + s*128 + kin] = f2bf(w1[i]);
}

__global__ void k_castw2(const float* __restrict__ w2, ushort* __restrict__ w2t){
  int i = blockIdx.x*256 + threadIdx.x;   // 32768
  int k = i & 127, np = i>>7;
  int s = np>>6, nn = np&63;
  float v = (nn<40) ? w2[(s*128 + k)*40 + nn] : 0.f;
  w2t[i] = f2bf(v);
}

// ------- SpMM width-128: one node per 16-lane group (4 nodes/wave) -------

#define FMA8(vv, ww) \
  a[0]+=ww*bflo(vv.x); a[1]+=ww*bfhi(vv.x); \
  a[2]+=ww*bflo(vv.y); a[3]+=ww*bfhi(vv.y); \
  a[4]+=ww*bflo(vv.z); a[5]+=ww*bfhi(vv.z); \
  a[6]+=ww*bflo(vv.w); a[7]+=ww*bfhi(vv.w);

__global__ void __launch_bounds__(256) k_spmm1(
    const ushort* __restrict__ src, ushort* __restrict__ dst,
    const int* __restrict__ rowptr, const uint2* __restrict__ ed, int N){
  int tid = threadIdx.x;
  int lane = tid & 63;
  int gl = tid & 15;              // lane in group; owns cols gl*8..gl*8+7
  int gbase = lane & 48;          // group's base lane in wave
  int n = blockIdx.x*16 + (tid>>4);
  if(n>=N) return;
  int s = rowptr[n], e = rowptr[n+1];
  float a[8];
  #pragma unroll
  for(int i=0;i<8;i++) a[i]=0.f;
  for(int b=s; b<e; b+=16){
    uint2 eD = make_uint2(0u,0u);
    if(b+gl < e) eD = ed[b+gl];
    #pragma unroll
    for(int t=0;t<4;t++){
      int j = gbase + 4*t;
      int r0 = __shfl((int)eD.x, j);
      int r1 = __shfl((int)eD.x, j+1);
      int r2 = __shfl((int)eD.x, j+2);
      int r3 = __shfl((int)eD.x, j+3);
      float w0 = __uint_as_float(__shfl((int)eD.y, j));
      float w1 = __uint_as_float(__shfl((int)eD.y, j+1));
      float w2 = __uint_as_float(__shfl((int)eD.y, j+2));
      float w3 = __uint_as_float(__shfl((int)eD.y, j+3));
      uint4 v0 = *(const uint4*)(src + (size_t)r0*128 + gl*8);
      uint4 v1 = *(const uint4*)(src + (size_t)r1*128 + gl*8);
      uint4 v2 = *(const uint4*)(src + (size_t)r2*128 + gl*8);
      uint4 v3 = *(const uint4*)(src + (size_t)r3*128 + gl*8);
      FMA8(v0, w0)
      FMA8(v1, w1)
      FMA8(v2, w2)
      FMA8(v3, w3)
    }
  }
  u32x4 o;
  o.x = (unsigned)f2bf(a[0]) | ((unsigned)f2bf(a[1])<<16);
  o.y = (unsigned)f2bf(a[2]) | ((unsigned)f2bf(a[3])<<16);
  o.z = (unsigned)f2bf(a[4]) | ((unsigned)f2bf(a[5])<<16);
  o.w = (unsigned)f2bf(a[6]) | ((unsigned)f2bf(a[7])<<16);
  __builtin_nontemporal_store(o, (u32x4*)(dst + (size_t)n*128 + gl*8));
}

// ------- SpMM width-64 + add z: one node per 8-lane group (8 nodes/wave) -------

__global__ void __launch_bounds__(256) k_spmm2(
    const ushort* __restrict__ tprev, int ss,
    const ushort* __restrict__ z, int zs,
    ushort* __restrict__ tnew,
    const int* __restrict__ rowptr, const uint2* __restrict__ ed, int N){
  int tid = threadIdx.x;
  int lane = tid & 63;
  int gl = tid & 7;               // lane in group; owns cols gl*8..gl*8+7
  int gbase = lane & 56;
  int n = blockIdx.x*32 + (tid>>3);
  if(n>=N) return;
  int s = rowptr[n], e = rowptr[n+1];
  float a[8];
  #pragma unroll
  for(int i=0;i<8;i++) a[i]=0.f;
  for(int b=s; b<e; b+=8){
    uint2 eD = make_uint2(0u,0u);
    if(b+gl < e) eD = ed[b+gl];
    #pragma unroll
    for(int t=0;t<2;t++){
      int j = gbase + 4*t;
      int r0 = __shfl((int)eD.x, j);
      int r1 = __shfl((int)eD.x, j+1);
      int r2 = __shfl((int)eD.x, j+2);
      int r3 = __shfl((int)eD.x, j+3);
      float w0 = __uint_as_float(__shfl((int)eD.y, j));
      float w1 = __uint_as_float(__shfl((int)eD.y, j+1));
      float w2 = __uint_as_float(__shfl((int)eD.y, j+2));
      float w3 = __uint_as_float(__shfl((int)eD.y, j+3));
      uint4 v0 = *(const uint4*)(tprev + (size_t)r0*ss + gl*8);
      uint4 v1 = *(const uint4*)(tprev + (size_t)r1*ss + gl*8);
      uint4 v2 = *(const uint4*)(tprev + (size_t)r2*ss + gl*8);
      uint4 v3 = *(const uint4*)(tprev + (size_t)r3*ss + gl*8);
      FMA8(v0, w0)
      FMA8(v1, w1)
      FMA8(v2, w2)
      FMA8(v3, w3)
    }
  }
  uint4 vz = *(const uint4*)(z + (size_t)n*zs + gl*8);
  a[0]+=bflo(vz.x); a[1]+=bfhi(vz.x);
  a[2]+=bflo(vz.y); a[3]+=bfhi(vz.y);
  a[4]+=bflo(vz.z); a[5]+=bfhi(vz.z);
  a[6]+=bflo(vz.w); a[7]+=bfhi(vz.w);
  u32x4 o;
  o.x = (unsigned)f2bf(a[0]) | ((unsigned)f2bf(a[1])<<16);
  o.y = (unsigned)f2bf(a[2]) | ((unsigned)f2bf(a[3])<<16);
  o.z = (unsigned)f2bf(a[4]) | ((unsigned)f2bf(a[5])<<16);
  o.w = (unsigned)f2bf(a[6]) | ((unsigned)f2bf(a[7])<<16);
  __builtin_nontemporal_store(o, (u32x4*)(tnew + (size_t)n*64 + gl*8));
}

// Final: out = log_softmax(A*tprev + z0) cols 0..39, f32 [N][40]; 8-lane group per node

__global__ void __launch_bounds__(256) k_spmm2_lsm(
    const ushort* __restrict__ tprev, int ss,
    const ushort* __restrict__ z, int zs,
    float* __restrict__ out,
    const int* __restrict__ rowptr, const uint2* __restrict__ ed, int N){
  int tid = threadIdx.x;
  int lane = tid & 63;
  int gl = tid & 7;
  int gbase = lane & 56;
  int n = blockIdx.x*32 + (tid>>3);
  if(n>=N) return;
  int s = rowptr[n], e = rowptr[n+1];
  float a[8];
  #pragma unroll
  for(int i=0;i<8;i++) a[i]=0.f;
  for(int b=s; b<e; b+=8){
    uint2 eD = make_uint2(0u,0u);
    if(b+gl < e) eD = ed[b+gl];
    #pragma unroll
    for(int t=0;t<2;t++){
      int j = gbase + 4*t;
      int r0 = __shfl((int)eD.x, j);
      int r1 = __shfl((int)eD.x, j+1);
      int r2 = __shfl((int)eD.x, j+2);
      int r3 = __shfl((int)eD.x, j+3);
      float w0 = __uint_as_float(__shfl((int)eD.y, j));
      float w1 = __uint_as_float(__shfl((int)eD.y, j+1));
      float w2 = __uint_as_float(__shfl((int)eD.y, j+2));
      float w3 = __uint_as_float(__shfl((int)eD.y, j+3));
      uint4 v0 = *(const uint4*)(tprev + (size_t)r0*ss + gl*8);
      uint4 v1 = *(const uint4*)(tprev + (size_t)r1*ss + gl*8);
      uint4 v2 = *(const uint4*)(tprev + (size_t)r2*ss + gl*8);
      uint4 v3 = *(const uint4*)(tprev + (size_t)r3*ss + gl*8);
      FMA8(v0, w0)
      FMA8(v1, w1)
      FMA8(v2, w2)
      FMA8(v3, w3)
    }
  }
  uint4 vz = *(const uint4*)(z + (size_t)n*zs + gl*8);
  a[0]+=bflo(vz.x); a[1]+=bfhi(vz.x);
  a[2]+=bflo(vz.y); a[3]+=bfhi(vz.y);
  a[4]+=bflo(vz.z); a[5]+=bfhi(vz.z);
  a[6]+=bflo(vz.w); a[7]+=bfhi(vz.w);
  bool valid = (gl < 5);          // cols 8gl..8gl+7 < 40
  float mx = -1e30f;
  #pragma unroll
  for(int i=0;i<8;i++) if(valid) mx = fmaxf(mx, a[i]);
  #pragma unroll
  for(int o=1;o<8;o<<=1) mx = fmaxf(mx, __shfl_xor(mx, o));
  float sum = 0.f;
  #pragma unroll
  for(int i=0;i<8;i++) if(valid) sum += __expf(a[i]-mx);
  #pragma unroll
  for(int o=1;o<8;o<<=1) sum += __shfl_xor(sum, o);
  float l = mx + __logf(sum);
  if(valid){
    f32x4 o0, o1;
    o0[0]=a[0]-l; o0[1]=a[1]-l; o0[2]=a[2]-l; o0[3]=a[3]-l;
    o1[0]=a[4]-l; o1[1]=a[5]-l; o1[2]=a[6]-l; o1[3]=a[7]-l;
    float* op = out + (size_t)n*40 + gl*8;
    __builtin_nontemporal_store(o0, (f32x4*)op);
    __builtin_nontemporal_store(o1, (f32x4*)(op+4));
  }
}

// ---------------- MFMA GEMM layer 1 ----------------

#define LDA 72

__global__ void __launch_bounds__(256) k_gemm1(
    const ushort* __restrict__ xb, const ushort* __restrict__ h1,
    const ushort* __restrict__ h2, const ushort* __restrict__ h3,
    const ushort* __restrict__ w1t, const float* __restrict__ bias,
    ushort* __restrict__ outb, int N){
  __shared__ ushort Al[128*LDA];
  __shared__ ushort Bl[128*LDA];
  int tid = threadIdx.x;
  int wid = tid>>6, lane = tid&63;
  int wr = wid>>1, wc = wid&1;
  int lm = lane&15, kg = lane>>4;
  int nbase = blockIdx.x*128;
  f32x4 acc[4][4];
  #pragma unroll
  for(int i=0;i<4;i++)
    #pragma unroll
    for(int j=0;j<4;j++) acc[i][j] = (f32x4){0.f,0.f,0.f,0.f};

  for(int kc=0; kc<8; kc++){
    const ushort* asrc = (kc<2) ? xb : (kc<4) ? h1 : (kc<6) ? h2 : h3;
    int koff = (kc&1)*64;
    __syncthreads();
    #pragma unroll
    for(int i=0;i<4;i++){
      int slot = tid + i*256;
      int r = slot>>3, seg = (slot&7)*8;
      int n = nbase + r;
      uint4 v = make_uint4(0,0,0,0);
      if(n < N) v = *(const uint4*)(asrc + (size_t)n*128 + koff + seg);
      *(uint4*)(&Al[r*LDA + seg]) = v;
    }
    #pragma unroll
    for(int i=0;i<4;i++){
      int slot = tid + i*256;
      int r = slot>>3, seg = (slot&7)*8;
      uint4 v = *(const uint4*)(w1t + (size_t)r*512 + kc*64 + seg);
      *(uint4*)(&Bl[r*LDA + seg]) = v;
    }
    __syncthreads();
    #pragma unroll
    for(int ks=0; ks<2; ks++){
      bf16x8 a[4], b[4];
      #pragma unroll
      for(int f=0; f<4; f++){
        a[f] = *(const bf16x8*)&Al[(wr*64 + f*16 + lm)*LDA + ks*32 + kg*8];
        b[f] = *(const bf16x8*)&Bl[(wc*64 + f*16 + lm)*LDA + ks*32 + kg*8];
      }
      #pragma unroll
      for(int fm=0; fm<4; fm++)
        #pragma unroll
        for(int fn=0; fn<4; fn++)
          acc[fm][fn] = __builtin_amdgcn_mfma_f32_16x16x32_bf16(a[fm], b[fn], acc[fm][fn], 0,0,0);
    }
  }
  int crow0 = (lane>>4)*4;
  #pragma unroll
  for(int fm=0; fm<4; fm++){
    #pragma unroll
    for(int fn=0; fn<4; fn++){
      int col = wc*64 + fn*16 + lm;
      float bv = bias[col];
      #pragma unroll
      for(int j=0;j<4;j++){
        int row = nbase + wr*64 + fm*16 + crow0 + j;
        if(row < N){
          float v = fmaxf(acc[fm][fn][j] + bv, 0.f);
          outb[(size_t)row*128 + col] = f2bf(v);
        }
      }
    }
  }
}

// ------- MFMA GEMM layer 2: zstack[N][256] = out1b @ W2t^T (+b2 on cols<40) -------

__global__ void __launch_bounds__(256) k_gemm2(
    const ushort* __restrict__ ab, const ushort* __restrict__ w2t,
    const float* __restrict__ bias, ushort* __restrict__ z, int N){
  __shared__ ushort Al[128*LDA];
  __shared__ ushort Bl[128*LDA];
  int tid = threadIdx.x;
  int wid = tid>>6, lane = tid&63;
  int wr = wid>>1, wc = wid&1;
  int lm = lane&15, kg = lane>>4;
  int nbase = blockIdx.x*128;
  int cb = blockIdx.y;
  f32x4 acc[4][4];
  #pragma unroll
  for(int i=0;i<4;i++)
    #pragma unroll
    for(int j=0;j<4;j++) acc[i][j] = (f32x4){0.f,0.f,0.f,0.f};

  for(int kc=0; kc<2; kc++){
    int koff = kc*64;
    __syncthreads();
    #pragma unroll
    for(int i=0;i<4;i++){
      int slot = tid + i*256;
      int r = slot>>3, seg = (slot&7)*8;
      int n = nbase + r;
      uint4 v = make_uint4(0,0,0,0);
      if(n < N) v = *(const uint4*)(ab + (size_t)n*128 + koff + seg);
      *(uint4*)(&Al[r*LDA + seg]) = v;
    }
    #pragma unroll
    for(int i=0;i<4;i++){
      int slot = tid + i*256;
      int r = slot>>3, seg = (slot&7)*8;
      uint4 v = *(const uint4*)(w2t + (size_t)(cb*128 + r)*128 + koff + seg);
      *(uint4*)(&Bl[r*LDA + seg]) = v;
    }
    __syncthreads();
    #pragma unroll
    for(int ks=0; ks<2; ks++){
      bf16x8 a[4], b[4];
      #pragma unroll
      for(int f=0; f<4; f++){
        a[f] = *(const bf16x8*)&Al[(wr*64 + f*16 + lm)*LDA + ks*32 + kg*8];
        b[f] = *(const bf16x8*)&Bl[(wc*64 + f*16 + lm)*LDA + ks*32 + kg*8];
      }
      #pragma unroll
      for(int fm=0; fm<4; fm++)
        #pragma unroll
        for(int fn=0; fn<4; fn++)
          acc[fm][fn] = __builtin_amdgcn_mfma_f32_16x16x32_bf16(a[fm], b[fn], acc[fm][fn], 0,0,0);
    }
  }
  int crow0 = (lane>>4)*4;
  #pragma unroll
  for(int fm=0; fm<4; fm++){
    #pragma unroll
    for(int fn=0; fn<4; fn++){
      int cc = cb*128 + wc*64 + fn*16 + lm;
      float bv = (cc < 40) ? bias[cc] : 0.f;
      #pragma unroll
      for(int j=0;j<4;j++){
        int row = nbase + wr*64 + fm*16 + crow0 + j;
        if(row < N){
          float v = acc[fm][fn][j] + bv;
          z[(size_t)row*256 + cc] = f2bf(v);
        }
      }
    }
  }
}

// ---------------- host ----------------

extern "C" void kernel_launch(void* const* d_in, const int* in_sizes, int n_in,
                              void* d_out, int out_size, void* d_ws, size_t ws_size,
                              hipStream_t stream){
  const float* x  = (const float*)d_in[0];
  const int*   ei = (const int*)d_in[1];
  const float* w1 = (const float*)d_in[2];
  const float* b1 = (const float*)d_in[3];
  const float* w2 = (const float*)d_in[4];
  const float* b2 = (const float*)d_in[5];
  float* out = (float*)d_out;
  int N = in_sizes[0] / 128;
  int E = in_sizes[1] / 2;
  const int* rowv = ei;
  const int* colv = ei + E;
  int NB = (N + 255) >> 8;

  char* wsp = (char*)d_ws;
  size_t off = 0;
  auto alloc = [&](size_t bytes)->void*{
    void* p = wsp + off;
    off = (off + bytes + 255) & ~(size_t)255;
    return p;
  };
  float*    dis    = (float*)   alloc((size_t)N*4);
  int*      rowptr = (int*)     alloc((size_t)(N+1)*4);
  int*      hcnt   = (int*)     alloc(512*4);
  int*      bbase  = (int*)     alloc(513*4);
  int*      gcur   = (int*)     alloc(512*4);
  unsigned* part   = (unsigned*)alloc((size_t)E*4);
  unsigned* ed4    = (unsigned*)alloc((size_t)E*4);
  uint2*    ed8    = (uint2*)   alloc((size_t)E*8);
  ushort*   xb     = (ushort*)  alloc((size_t)N*128*2);
  ushort*   hb1    = (ushort*)  alloc((size_t)N*128*2);
  ushort*   hb2    = (ushort*)  alloc((size_t)N*128*2);
  ushort*   hb3    = (ushort*)  alloc((size_t)N*128*2);
  ushort*   out1b  = (ushort*)  alloc((size_t)N*128*2);
  ushort*   w1t    = (ushort*)  alloc(128*512*2);
  ushort*   w2t    = (ushort*)  alloc(256*128*2);
  ushort*   zst    = (ushort*)  alloc((size_t)N*256*2);
  ushort*   ta     = hb1;   // dead after k_gemm1
  ushort*   tb     = hb2;
  (void)ws_size;

  int pb = (E+PT-1)/PT;
  int sg  = (N+3)/4;
  int sg1 = (N+15)/16;
  int sg2 = (N+31)/32;
  int gb  = (N+127)/128;

  hipMemsetAsync(hcnt, 0, 512*4, stream);
  k_phist <<<pb, 256, 0, stream>>>(colv, hcnt, E);
  k_bscan <<<1, 512, 0, stream>>>(hcnt, bbase, gcur, rowptr, NB, N);
  k_part  <<<pb, 256, 0, stream>>>(rowv, colv, gcur, part, E);
  k_csort <<<NB, 256, 0, stream>>>(part, bbase, dis, ed4, rowptr, N);
  k_wfill <<<sg, 256, 0, stream>>>(ed4, rowptr, dis, ed8, N);

  k_cast_x <<<(N*32+255)/256, 256, 0, stream>>>(x, xb, N*32);
  k_castw1 <<<256, 256, 0, stream>>>(w1, w1t);
  k_castw2 <<<128, 256, 0, stream>>>(w2, w2t);

  // layer 1: propagate width-128 bf16
  k_spmm1<<<sg1, 256, 0, stream>>>(xb,  hb1, rowptr, ed8, N);
  k_spmm1<<<sg1, 256, 0, stream>>>(hb1, hb2, rowptr, ed8, N);
  k_spmm1<<<sg1, 256, 0, stream>>>(hb2, hb3, rowptr, ed8, N);
  k_gemm1<<<gb, 256, 0, stream>>>(xb, hb1, hb2, hb3, w1t, b1, out1b, N);
  // layer 2: z_k = H @ W2_k, then Horner propagation at width 64
  k_gemm2<<<dim3(gb,2), 256, 0, stream>>>(out1b, w2t, b2, zst, N);
  k_spmm2    <<<sg2, 256, 0, stream>>>(zst+192, 256, zst+128, 256, ta, rowptr, ed8, N);
  k_spmm2    <<<sg2, 256, 0, stream>>>(ta,       64, zst+64,  256, tb, rowptr, ed8, N);
  k_spmm2_lsm<<<sg2, 256, 0, stream>>>(tb,       64, zst,     256, out, rowptr, ed8, N);
}

// Round 12
// 439.132 us; speedup vs baseline: 1.5006x; 1.0654x over previous
//
#include <hip/hip_runtime.h>
#include <math.h>

typedef __bf16 bf16x8 __attribute__((ext_vector_type(8)));
typedef float  f32x4  __attribute__((ext_vector_type(4)));
typedef unsigned u32x4 __attribute__((ext_vector_type(4)));

__device__ __forceinline__ unsigned short f2bf(float f){
  unsigned u = __float_as_uint(f);
  unsigned r = (u + 0x7fffu + ((u>>16)&1u)) >> 16;
  return (unsigned short)r;
}
__device__ __forceinline__ float bflo(unsigned v){ return __uint_as_float(v<<16); }
__device__ __forceinline__ float bfhi(unsigned v){ return __uint_as_float(v & 0xffff0000u); }

__device__ __forceinline__ void gl_lds16(const void* g, void* l){
  __builtin_amdgcn_global_load_lds((const __attribute__((address_space(1))) void*)g,
                                   (__attribute__((address_space(3))) void*)l, 16, 0, 0);
}

// ---------------- bucket histogram (256-node buckets) ----------------

#define PT 8192

__global__ void __launch_bounds__(256) k_phist(const int* __restrict__ colv,
                                               int* __restrict__ hcnt, int E){
  __shared__ int lh[512];
  int tid = threadIdx.x;
  for(int i=tid;i<512;i+=256) lh[i]=0;
  __syncthreads();
  int base = blockIdx.x*PT;
  int bmax = E - base; if(bmax > PT) bmax = PT;
  for(int k=tid;k<bmax;k+=256){
    int c = colv[base+k];
    atomicAdd(&lh[c>>8],1);
  }
  __syncthreads();
  for(int i=tid;i<512;i+=256){
    int cnt = lh[i];
    if(cnt>0) atomicAdd(&hcnt[i],cnt);
  }
}

// single block: scan hcnt -> bbase[513], init gcur, rowptr[N]=E
__global__ void __launch_bounds__(512) k_bscan(const int* __restrict__ hcnt,
                                               int* __restrict__ bbase, int* __restrict__ gcur,
                                               int* __restrict__ rowptr, int NB, int N){
  __shared__ int ts[512];
  int tid = threadIdx.x;
  int v = (tid<NB) ? hcnt[tid] : 0;
  ts[tid]=v; __syncthreads();
  for(int o=1;o<512;o<<=1){
    int t=(tid>=o)?ts[tid-o]:0; __syncthreads();
    ts[tid]+=t; __syncthreads();
  }
  int ex = ts[tid]-v;
  if(tid<=NB) bbase[tid] = (tid<NB) ? ex : ts[NB-1];
  if(tid<NB)  gcur[tid]  = ex;
  if(tid==0)  rowptr[N]  = ts[511];
}

// ---------------- partition into buckets: part[pos] = (colLow8<<24) | src ----------------

__global__ void __launch_bounds__(256) k_part(const int* __restrict__ rowv,
                                              const int* __restrict__ colv,
                                              int* __restrict__ gcur,
                                              unsigned* __restrict__ part, int E){
  __shared__ int lh[512];
  __shared__ int lb[512];
  int tid = threadIdx.x;
  for(int i=tid;i<512;i+=256) lh[i]=0;
  __syncthreads();
  int base = blockIdx.x*PT;
  int bmax = E - base; if(bmax > PT) bmax = PT;
  for(int k=tid;k<bmax;k+=256){
    int c = colv[base+k];
    atomicAdd(&lh[c>>8],1);
  }
  __syncthreads();
  for(int i=tid;i<512;i+=256){
    int cnt = lh[i];
    lb[i] = cnt>0 ? atomicAdd(&gcur[i],cnt) : 0;
  }
  __syncthreads();
  for(int i=tid;i<512;i+=256) lh[i]=0;
  __syncthreads();
  for(int k=tid;k<bmax;k+=256){
    int r = rowv[base+k], c = colv[base+k];
    int b = c>>8;
    int pos = lb[b] + atomicAdd(&lh[b],1);
    part[pos] = ((unsigned)(c&255)<<24) | (unsigned)r;
  }
}

// ------- per-bucket counting sort -> ed4 (src), rowptr, dis -------

#define CAP 6144

__global__ void __launch_bounds__(256) k_csort(const unsigned* __restrict__ part,
                                               const int* __restrict__ bbase,
                                               float* __restrict__ dis,
                                               unsigned* __restrict__ ed4,
                                               int* __restrict__ rowptr, int N){
  __shared__ unsigned st[CAP];
  __shared__ int cnt[256];
  __shared__ int ts[256];
  int b = blockIdx.x, tid = threadIdx.x;
  int nb0 = b<<8;
  int g0 = bbase[b], g1 = bbase[b+1];
  int ce = g1-g0;
  cnt[tid]=0; __syncthreads();
  for(int i=tid;i<ce;i+=256){
    atomicAdd(&cnt[part[g0+i]>>24],1);
  }
  __syncthreads();
  int v = cnt[tid];
  ts[tid]=v; __syncthreads();
  for(int o=1;o<256;o<<=1){
    int t=(tid>=o)?ts[tid-o]:0; __syncthreads();
    ts[tid]+=t; __syncthreads();
  }
  int ex = ts[tid]-v;
  int node = nb0+tid;
  if(node < N){
    rowptr[node] = g0 + ex;
    dis[node] = v > 0 ? rsqrtf((float)v) : 0.f;
  }
  cnt[tid] = ex;
  __syncthreads();
  for(int i=tid;i<ce;i+=256){
    unsigned pc = part[g0+i];
    int pos = atomicAdd(&cnt[pc>>24],1);
    if(pos < CAP) st[pos] = pc & 0xFFFFFFu;
  }
  __syncthreads();
  for(int i=tid;i<ce;i+=256) ed4[g0+i] = st[i];
}

// ------- weight fill: ed8[e] = {src, dis[src]*dis[n]}, coalesced -------

__global__ void __launch_bounds__(256) k_wfill(const unsigned* __restrict__ ed4,
                                               const int* __restrict__ rowptr,
                                               const float* __restrict__ dis,
                                               uint2* __restrict__ ed8, int N){
  int wid = threadIdx.x>>6, lane = threadIdx.x&63;
  int n = blockIdx.x*4 + wid;
  if(n>=N) return;
  int s = rowptr[n], e = rowptr[n+1];
  float dc = dis[n];
  for(int i=s+lane; i<e; i+=64){
    unsigned r = ed4[i];
    ed8[i] = make_uint2(r, __float_as_uint(dis[r]*dc));
  }
}

// ---------------- merged casts ----------------

__global__ void k_cast_all(const float* __restrict__ x, const float* __restrict__ w1,
                           const float* __restrict__ w2, ushort* __restrict__ xb,
                           ushort* __restrict__ w1t, ushort* __restrict__ w2t, int n4){
  int t = blockIdx.x*256 + threadIdx.x;
  if(t < n4){
    float4 v = ((const float4*)x)[t];
    uint2 o;
    o.x = (unsigned)f2bf(v.x) | ((unsigned)f2bf(v.y)<<16);
    o.y = (unsigned)f2bf(v.z) | ((unsigned)f2bf(v.w)<<16);
    ((uint2*)xb)[t] = o;
  }
  if(t < 65536){
    int n = t & 127, kin = (t>>7)&127, s = t>>14;
    w1t[n*512 + s*128 + kin] = f2bf(w1[t]);
  }
  if(t < 32768){
    int k = t & 127, np = t>>7;
    int s = np>>6, nn = np&63;
    float v = (nn<40) ? w2[(s*128 + k)*40 + nn] : 0.f;
    w2t[t] = f2bf(v);
  }
}

// ------- SpMM width-128: one node per 16-lane group (4 nodes/wave) -------

#define FMA8(vv, ww) \
  a[0]+=ww*bflo(vv.x); a[1]+=ww*bfhi(vv.x); \
  a[2]+=ww*bflo(vv.y); a[3]+=ww*bfhi(vv.y); \
  a[4]+=ww*bflo(vv.z); a[5]+=ww*bfhi(vv.z); \
  a[6]+=ww*bflo(vv.w); a[7]+=ww*bfhi(vv.w);

__global__ void __launch_bounds__(256) k_spmm1(
    const ushort* __restrict__ src, ushort* __restrict__ dst,
    const int* __restrict__ rowptr, const uint2* __restrict__ ed, int N){
  int tid = threadIdx.x;
  int lane = tid & 63;
  int gl = tid & 15;
  int gbase = lane & 48;
  int n = blockIdx.x*16 + (tid>>4);
  if(n>=N) return;
  int s = rowptr[n], e = rowptr[n+1];
  float a[8];
  #pragma unroll
  for(int i=0;i<8;i++) a[i]=0.f;
  for(int b=s; b<e; b+=16){
    uint2 eD = make_uint2(0u,0u);
    if(b+gl < e) eD = ed[b+gl];
    #pragma unroll
    for(int t=0;t<4;t++){
      int j = gbase + 4*t;
      int r0 = __shfl((int)eD.x, j);
      int r1 = __shfl((int)eD.x, j+1);
      int r2 = __shfl((int)eD.x, j+2);
      int r3 = __shfl((int)eD.x, j+3);
      float w0 = __uint_as_float(__shfl((int)eD.y, j));
      float w1 = __uint_as_float(__shfl((int)eD.y, j+1));
      float w2 = __uint_as_float(__shfl((int)eD.y, j+2));
      float w3 = __uint_as_float(__shfl((int)eD.y, j+3));
      uint4 v0 = *(const uint4*)(src + (size_t)r0*128 + gl*8);
      uint4 v1 = *(const uint4*)(src + (size_t)r1*128 + gl*8);
      uint4 v2 = *(const uint4*)(src + (size_t)r2*128 + gl*8);
      uint4 v3 = *(const uint4*)(src + (size_t)r3*128 + gl*8);
      FMA8(v0, w0)
      FMA8(v1, w1)
      FMA8(v2, w2)
      FMA8(v3, w3)
    }
  }
  u32x4 o;
  o.x = (unsigned)f2bf(a[0]) | ((unsigned)f2bf(a[1])<<16);
  o.y = (unsigned)f2bf(a[2]) | ((unsigned)f2bf(a[3])<<16);
  o.z = (unsigned)f2bf(a[4]) | ((unsigned)f2bf(a[5])<<16);
  o.w = (unsigned)f2bf(a[6]) | ((unsigned)f2bf(a[7])<<16);
  __builtin_nontemporal_store(o, (u32x4*)(dst + (size_t)n*128 + gl*8));
}

// ------- SpMM width-64 + add z: one node per 8-lane group (8 nodes/wave) -------

__global__ void __launch_bounds__(256) k_spmm2(
    const ushort* __restrict__ tprev, int ss,
    const ushort* __restrict__ z, int zs,
    ushort* __restrict__ tnew,
    const int* __restrict__ rowptr, const uint2* __restrict__ ed, int N){
  int tid = threadIdx.x;
  int lane = tid & 63;
  int gl = tid & 7;
  int gbase = lane & 56;
  int n = blockIdx.x*32 + (tid>>3);
  if(n>=N) return;
  int s = rowptr[n], e = rowptr[n+1];
  float a[8];
  #pragma unroll
  for(int i=0;i<8;i++) a[i]=0.f;
  for(int b=s; b<e; b+=8){
    uint2 eD = make_uint2(0u,0u);
    if(b+gl < e) eD = ed[b+gl];
    #pragma unroll
    for(int t=0;t<2;t++){
      int j = gbase + 4*t;
      int r0 = __shfl((int)eD.x, j);
      int r1 = __shfl((int)eD.x, j+1);
      int r2 = __shfl((int)eD.x, j+2);
      int r3 = __shfl((int)eD.x, j+3);
      float w0 = __uint_as_float(__shfl((int)eD.y, j));
      float w1 = __uint_as_float(__shfl((int)eD.y, j+1));
      float w2 = __uint_as_float(__shfl((int)eD.y, j+2));
      float w3 = __uint_as_float(__shfl((int)eD.y, j+3));
      uint4 v0 = *(const uint4*)(tprev + (size_t)r0*ss + gl*8);
      uint4 v1 = *(const uint4*)(tprev + (size_t)r1*ss + gl*8);
      uint4 v2 = *(const uint4*)(tprev + (size_t)r2*ss + gl*8);
      uint4 v3 = *(const uint4*)(tprev + (size_t)r3*ss + gl*8);
      FMA8(v0, w0)
      FMA8(v1, w1)
      FMA8(v2, w2)
      FMA8(v3, w3)
    }
  }
  uint4 vz = *(const uint4*)(z + (size_t)n*zs + gl*8);
  a[0]+=bflo(vz.x); a[1]+=bfhi(vz.x);
  a[2]+=bflo(vz.y); a[3]+=bfhi(vz.y);
  a[4]+=bflo(vz.z); a[5]+=bfhi(vz.z);
  a[6]+=bflo(vz.w); a[7]+=bfhi(vz.w);
  u32x4 o;
  o.x = (unsigned)f2bf(a[0]) | ((unsigned)f2bf(a[1])<<16);
  o.y = (unsigned)f2bf(a[2]) | ((unsigned)f2bf(a[3])<<16);
  o.z = (unsigned)f2bf(a[4]) | ((unsigned)f2bf(a[5])<<16);
  o.w = (unsigned)f2bf(a[6]) | ((unsigned)f2bf(a[7])<<16);
  __builtin_nontemporal_store(o, (u32x4*)(tnew + (size_t)n*64 + gl*8));
}

// Final: out = log_softmax(A*tprev + z0) cols 0..39, f32 [N][40]; 8-lane group per node

__global__ void __launch_bounds__(256) k_spmm2_lsm(
    const ushort* __restrict__ tprev, int ss,
    const ushort* __restrict__ z, int zs,
    float* __restrict__ out,
    const int* __restrict__ rowptr, const uint2* __restrict__ ed, int N){
  int tid = threadIdx.x;
  int lane = tid & 63;
  int gl = tid & 7;
  int gbase = lane & 56;
  int n = blockIdx.x*32 + (tid>>3);
  if(n>=N) return;
  int s = rowptr[n], e = rowptr[n+1];
  float a[8];
  #pragma unroll
  for(int i=0;i<8;i++) a[i]=0.f;
  for(int b=s; b<e; b+=8){
    uint2 eD = make_uint2(0u,0u);
    if(b+gl < e) eD = ed[b+gl];
    #pragma unroll
    for(int t=0;t<2;t++){
      int j = gbase + 4*t;
      int r0 = __shfl((int)eD.x, j);
      int r1 = __shfl((int)eD.x, j+1);
      int r2 = __shfl((int)eD.x, j+2);
      int r3 = __shfl((int)eD.x, j+3);
      float w0 = __uint_as_float(__shfl((int)eD.y, j));
      float w1 = __uint_as_float(__shfl((int)eD.y, j+1));
      float w2 = __uint_as_float(__shfl((int)eD.y, j+2));
      float w3 = __uint_as_float(__shfl((int)eD.y, j+3));
      uint4 v0 = *(const uint4*)(tprev + (size_t)r0*ss + gl*8);
      uint4 v1 = *(const uint4*)(tprev + (size_t)r1*ss + gl*8);
      uint4 v2 = *(const uint4*)(tprev + (size_t)r2*ss + gl*8);
      uint4 v3 = *(const uint4*)(tprev + (size_t)r3*ss + gl*8);
      FMA8(v0, w0)
      FMA8(v1, w1)
      FMA8(v2, w2)
      FMA8(v3, w3)
    }
  }
  uint4 vz = *(const uint4*)(z + (size_t)n*zs + gl*8);
  a[0]+=bflo(vz.x); a[1]+=bfhi(vz.x);
  a[2]+=bflo(vz.y); a[3]+=bfhi(vz.y);
  a[4]+=bflo(vz.z); a[5]+=bfhi(vz.z);
  a[6]+=bflo(vz.w); a[7]+=bfhi(vz.w);
  bool valid = (gl < 5);
  float mx = -1e30f;
  #pragma unroll
  for(int i=0;i<8;i++) if(valid) mx = fmaxf(mx, a[i]);
  #pragma unroll
  for(int o=1;o<8;o<<=1) mx = fmaxf(mx, __shfl_xor(mx, o));
  float sum = 0.f;
  #pragma unroll
  for(int i=0;i<8;i++) if(valid) sum += __expf(a[i]-mx);
  #pragma unroll
  for(int o=1;o<8;o<<=1) sum += __shfl_xor(sum, o);
  float l = mx + __logf(sum);
  if(valid){
    f32x4 o0, o1;
    o0[0]=a[0]-l; o0[1]=a[1]-l; o0[2]=a[2]-l; o0[3]=a[3]-l;
    o1[0]=a[4]-l; o1[1]=a[5]-l; o1[2]=a[6]-l; o1[3]=a[7]-l;
    float* op = out + (size_t)n*40 + gl*8;
    __builtin_nontemporal_store(o0, (f32x4*)op);
    __builtin_nontemporal_store(o1, (f32x4*)(op+4));
  }
}

// ---------------- MFMA GEMM layer 1 (global_load_lds + XOR-swizzled linear LDS) ----------------
// LDS content at byte (r*128 + b) = global chunk byte (b ^ ((r&7)<<4)) of row r.

__global__ void __launch_bounds__(256) k_gemm1(
    const ushort* __restrict__ xb, const ushort* __restrict__ h1,
    const ushort* __restrict__ h2, const ushort* __restrict__ h3,
    const ushort* __restrict__ w1t, const float* __restrict__ bias,
    ushort* __restrict__ outb, int N){
  __shared__ ushort Al[128*64];
  __shared__ ushort Bl[128*64];
  int tid = threadIdx.x;
  int w = tid>>6, lane = tid&63;
  int wr = w>>1, wc = w&1;
  int lm = lane&15, kg = lane>>4;
  int nbase = blockIdx.x*128;
  bool full = (nbase + 128 <= N);
  f32x4 acc[4][4];
  #pragma unroll
  for(int i=0;i<4;i++)
    #pragma unroll
    for(int j=0;j<4;j++) acc[i][j] = (f32x4){0.f,0.f,0.f,0.f};

  for(int kc=0; kc<8; kc++){
    const ushort* asrc = (kc<2) ? xb : (kc<4) ? h1 : (kc<6) ? h2 : h3;
    int koff = (kc&1)*64;
    __syncthreads();
    if(full){
      #pragma unroll
      for(int i=0;i<4;i++){
        int o = ((i*4 + w)*64 + lane)*16;
        int r = o>>7, b = o&127;
        int sb = b ^ ((r&7)<<4);
        gl_lds16((const char*)asrc + (size_t)(nbase + r)*256 + koff*2 + sb,
                 (char*)Al + (i*4 + w)*1024);
      }
      #pragma unroll
      for(int i=0;i<4;i++){
        int o = ((i*4 + w)*64 + lane)*16;
        int r = o>>7, b = o&127;
        int sb = b ^ ((r&7)<<4);
        gl_lds16((const char*)w1t + (size_t)r*1024 + kc*128 + sb,
                 (char*)Bl + (i*4 + w)*1024);
      }
    } else {
      #pragma unroll
      for(int i=0;i<4;i++){
        int slot = tid + i*256;
        int r = slot>>3, b = (slot&7)*16;
        int n = nbase + r;
        uint4 v = make_uint4(0,0,0,0);
        if(n < N) v = *(const uint4*)((const char*)asrc + (size_t)n*256 + koff*2 + b);
        *(uint4*)((char*)Al + r*128 + (b ^ ((r&7)<<4))) = v;
      }
      #pragma unroll
      for(int i=0;i<4;i++){
        int slot = tid + i*256;
        int r = slot>>3, b = (slot&7)*16;
        uint4 v = *(const uint4*)((const char*)w1t + (size_t)r*1024 + kc*128 + b);
        *(uint4*)((char*)Bl + r*128 + (b ^ ((r&7)<<4))) = v;
      }
    }
    __syncthreads();
    #pragma unroll
    for(int ks=0; ks<2; ks++){
      bf16x8 a[4], b[4];
      #pragma unroll
      for(int f=0; f<4; f++){
        int ra = wr*64 + f*16 + lm;
        int rb = wc*64 + f*16 + lm;
        int cb = ks*64 + kg*16;
        a[f] = *(const bf16x8*)((const char*)Al + ra*128 + (cb ^ ((ra&7)<<4)));
        b[f] = *(const bf16x8*)((const char*)Bl + rb*128 + (cb ^ ((rb&7)<<4)));
      }
      #pragma unroll
      for(int fm=0; fm<4; fm++)
        #pragma unroll
        for(int fn=0; fn<4; fn++)
          acc[fm][fn] = __builtin_amdgcn_mfma_f32_16x16x32_bf16(a[fm], b[fn], acc[fm][fn], 0,0,0);
    }
  }
  int crow0 = (lane>>4)*4;
  #pragma unroll
  for(int fm=0; fm<4; fm++){
    #pragma unroll
    for(int fn=0; fn<4; fn++){
      int col = wc*64 + fn*16 + lm;
      float bv = bias[col];
      #pragma unroll
      for(int j=0;j<4;j++){
        int row = nbase + wr*64 + fm*16 + crow0 + j;
        if(row < N){
          float v = fmaxf(acc[fm][fn][j] + bv, 0.f);
          outb[(size_t)row*128 + col] = f2bf(v);
        }
      }
    }
  }
}

// ------- MFMA GEMM layer 2: zstack[N][256] = out1b @ W2t^T (+b2 on cols<40) -------

__global__ void __launch_bounds__(256) k_gemm2(
    const ushort* __restrict__ ab, const ushort* __restrict__ w2t,
    const float* __restrict__ bias, ushort* __restrict__ z, int N){
  __shared__ ushort Al[128*64];
  __shared__ ushort Bl[128*64];
  int tid = threadIdx.x;
  int w = tid>>6, lane = tid&63;
  int wr = w>>1, wc = w&1;
  int lm = lane&15, kg = lane>>4;
  int nbase = blockIdx.x*128;
  int cb2 = blockIdx.y;
  bool full = (nbase + 128 <= N);
  f32x4 acc[4][4];
  #pragma unroll
  for(int i=0;i<4;i++)
    #pragma unroll
    for(int j=0;j<4;j++) acc[i][j] = (f32x4){0.f,0.f,0.f,0.f};

  for(int kc=0; kc<2; kc++){
    int koff = kc*64;
    __syncthreads();
    if(full){
      #pragma unroll
      for(int i=0;i<4;i++){
        int o = ((i*4 + w)*64 + lane)*16;
        int r = o>>7, b = o&127;
        int sb = b ^ ((r&7)<<4);
        gl_lds16((const char*)ab + (size_t)(nbase + r)*256 + koff*2 + sb,
                 (char*)Al + (i*4 + w)*1024);
      }
      #pragma unroll
      for(int i=0;i<4;i++){
        int o = ((i*4 + w)*64 + lane)*16;
        int r = o>>7, b = o&127;
        int sb = b ^ ((r&7)<<4);
        gl_lds16((const char*)w2t + (size_t)(cb2*128 + r)*256 + koff*2 + sb,
                 (char*)Bl + (i*4 + w)*1024);
      }
    } else {
      #pragma unroll
      for(int i=0;i<4;i++){
        int slot = tid + i*256;
        int r = slot>>3, b = (slot&7)*16;
        int n = nbase + r;
        uint4 v = make_uint4(0,0,0,0);
        if(n < N) v = *(const uint4*)((const char*)ab + (size_t)n*256 + koff*2 + b);
        *(uint4*)((char*)Al + r*128 + (b ^ ((r&7)<<4))) = v;
      }
      #pragma unroll
      for(int i=0;i<4;i++){
        int slot = tid + i*256;
        int r = slot>>3, b = (slot&7)*16;
        uint4 v = *(const uint4*)((const char*)w2t + (size_t)(cb2*128 + r)*256 + koff*2 + b);
        *(uint4*)((char*)Bl + r*128 + (b ^ ((r&7)<<4))) = v;
      }
    }
    __syncthreads();
    #pragma unroll
    for(int ks=0; ks<2; ks++){
      bf16x8 a[4], b[4];
      #pragma unroll
      for(int f=0; f<4; f++){
        int ra = wr*64 + f*16 + lm;
        int rb = wc*64 + f*16 + lm;
        int cbyte = ks*64 + kg*16;
        a[f] = *(const bf16x8*)((const char*)Al + ra*128 + (cbyte ^ ((ra&7)<<4)));
        b[f] = *(const bf16x8*)((const char*)Bl + rb*128 + (cbyte ^ ((rb&7)<<4)));
      }
      #pragma unroll
      for(int fm=0; fm<4; fm++)
        #pragma unroll
        for(int fn=0; fn<4; fn++)
          acc[fm][fn] = __builtin_amdgcn_mfma_f32_16x16x32_bf16(a[fm], b[fn], acc[fm][fn], 0,0,0);
    }
  }
  int crow0 = (lane>>4)*4;
  #pragma unroll
  for(int fm=0; fm<4; fm++){
    #pragma unroll
    for(int fn=0; fn<4; fn++){
      int cc = cb2*128 + wc*64 + fn*16 + lm;
      float bv = (cc < 40) ? bias[cc] : 0.f;
      #pragma unroll
      for(int j=0;j<4;j++){
        int row = nbase + wr*64 + fm*16 + crow0 + j;
        if(row < N){
          float v = acc[fm][fn][j] + bv;
          z[(size_t)row*256 + cc] = f2bf(v);
        }
      }
    }
  }
}

// ---------------- host ----------------

extern "C" void kernel_launch(void* const* d_in, const int* in_sizes, int n_in,
                              void* d_out, int out_size, void* d_ws, size_t ws_size,
                              hipStream_t stream){
  const float* x  = (const float*)d_in[0];
  const int*   ei = (const int*)d_in[1];
  const float* w1 = (const float*)d_in[2];
  const float* b1 = (const float*)d_in[3];
  const float* w2 = (const float*)d_in[4];
  const float* b2 = (const float*)d_in[5];
  float* out = (float*)d_out;
  int N = in_sizes[0] / 128;
  int E = in_sizes[1] / 2;
  const int* rowv = ei;
  const int* colv = ei + E;
  int NB = (N + 255) >> 8;

  char* wsp = (char*)d_ws;
  size_t off = 0;
  auto alloc = [&](size_t bytes)->void*{
    void* p = wsp + off;
    off = (off + bytes + 255) & ~(size_t)255;
    return p;
  };
  float*    dis    = (float*)   alloc((size_t)N*4);
  int*      rowptr = (int*)     alloc((size_t)(N+1)*4);
  int*      hcnt   = (int*)     alloc(512*4);
  int*      bbase  = (int*)     alloc(513*4);
  int*      gcur   = (int*)     alloc(512*4);
  unsigned* part   = (unsigned*)alloc((size_t)E*4);
  unsigned* ed4    = (unsigned*)alloc((size_t)E*4);
  uint2*    ed8    = (uint2*)   alloc((size_t)E*8);
  ushort*   xb     = (ushort*)  alloc((size_t)N*128*2);
  ushort*   hb1    = (ushort*)  alloc((size_t)N*128*2);
  ushort*   hb2    = (ushort*)  alloc((size_t)N*128*2);
  ushort*   hb3    = (ushort*)  alloc((size_t)N*128*2);
  ushort*   out1b  = (ushort*)  alloc((size_t)N*128*2);
  ushort*   w1t    = (ushort*)  alloc(128*512*2);
  ushort*   w2t    = (ushort*)  alloc(256*128*2);
  ushort*   zst    = (ushort*)  alloc((size_t)N*256*2);
  ushort*   ta     = hb1;   // dead after k_gemm1
  ushort*   tb     = hb2;
  (void)ws_size;

  int pb = (E+PT-1)/PT;
  int sg  = (N+3)/4;
  int sg1 = (N+15)/16;
  int sg2 = (N+31)/32;
  int gb  = (N+127)/128;

  hipMemsetAsync(hcnt, 0, 512*4, stream);
  k_phist <<<pb, 256, 0, stream>>>(colv, hcnt, E);
  k_bscan <<<1, 512, 0, stream>>>(hcnt, bbase, gcur, rowptr, NB, N);
  k_part  <<<pb, 256, 0, stream>>>(rowv, colv, gcur, part, E);
  k_csort <<<NB, 256, 0, stream>>>(part, bbase, dis, ed4, rowptr, N);
  k_wfill <<<sg, 256, 0, stream>>>(ed4, rowptr, dis, ed8, N);

  k_cast_all<<<(N*32+255)/256, 256, 0, stream>>>(x, w1, w2, xb, w1t, w2t, N*32);

  // layer 1: propagate width-128 bf16
  k_spmm1<<<sg1, 256, 0, stream>>>(xb,  hb1, rowptr, ed8, N);
  k_spmm1<<<sg1, 256, 0, stream>>>(hb1, hb2, rowptr, ed8, N);
  k_spmm1<<<sg1, 256, 0, stream>>>(hb2, hb3, rowptr, ed8, N);
  k_gemm1<<<gb, 256, 0, stream>>>(xb, hb1, hb2, hb3, w1t, b1, out1b, N);
  // layer 2: z_k = H @ W2_k, then Horner propagation at width 64
  k_gemm2<<<dim3(gb,2), 256, 0, stream>>>(out1b, w2t, b2, zst, N);
  k_spmm2    <<<sg2, 256, 0, stream>>>(zst+192, 256, zst+128, 256, ta, rowptr, ed8, N);
  k_spmm2    <<<sg2, 256, 0, stream>>>(ta,       64, zst+64,  256, tb, rowptr, ed8, N);
  k_spmm2_lsm<<<sg2, 256, 0, stream>>>(tb,       64, zst,     256, out, rowptr, ed8, N);
}